// Round 1
// baseline (817.478 us; speedup 1.0000x reference)
//
#include <hip/hip_runtime.h>

#define N_PTS 50000
#define M 32        // neighbors
#define KP 15       // kernel points
#define D_IN 64
#define D_OUT 64
#define E1 45       // offset dim = 3*KP
#define P 8         // points per block

// extent = POINT_INFLUENCE = 1.0 (aw = max(1 - dist, 0)); offsets scaled by 1.0

__global__ __launch_bounds__(256, 2) void kpconv_deform(
    const float* __restrict__ qpts,      // [N,3]
    const float* __restrict__ spts,      // [N,3]
    const int*   __restrict__ nbrs,      // [N,M]
    const float* __restrict__ x,         // [N,64]
    const float* __restrict__ kpts,      // [15,3]
    const float* __restrict__ ow,        // [15,64,45]
    const float* __restrict__ obias,     // [45]
    const float* __restrict__ w,         // [15,64,64]
    float* __restrict__ out)             // [N,64]
{
    __shared__ int   s_nbr[P][M];
    __shared__ float s_nb[P][M][3];
    __shared__ float s_kp[KP][3];
    __shared__ float s_q[P][3];
    __shared__ float s_aw[P][KP][M];          // 15 KB (aw1 then aw2)
    __shared__ float s_wf[P][KP * D_IN];      // 30 KB (wf1 then wf2)
    __shared__ float s_off[P][E1];
    __shared__ float s_part[4][P][64];        // matmul partial sums

    const int tid  = threadIdx.x;
    const int base = blockIdx.x * P;          // first point of this block

    // ---- stage tiny constants ----
    if (tid < KP * 3) ((float*)s_kp)[tid] = kpts[tid];
    if (tid < P * 3)  ((float*)s_q)[tid]  = qpts[base * 3 + tid];
    __syncthreads();

    // ---- phase 0/1: gather neighbors, centered nb, aw1 ----
    {
        const int p = tid >> 5, m = tid & 31;
        const int nb_idx = nbrs[(base + p) * M + m];
        s_nbr[p][m] = nb_idx;
        const float nbx = spts[nb_idx * 3 + 0] - s_q[p][0];
        const float nby = spts[nb_idx * 3 + 1] - s_q[p][1];
        const float nbz = spts[nb_idx * 3 + 2] - s_q[p][2];
        s_nb[p][m][0] = nbx; s_nb[p][m][1] = nby; s_nb[p][m][2] = nbz;
        #pragma unroll
        for (int k = 0; k < KP; k++) {
            const float dx = nbx - s_kp[k][0];
            const float dy = nby - s_kp[k][1];
            const float dz = nbz - s_kp[k][2];
            const float d  = sqrtf(dx * dx + dy * dy + dz * dz);
            s_aw[p][k][m] = fmaxf(1.0f - d, 0.0f);
        }
    }
    __syncthreads();

    // ---- phase 2: wf1[p][k*64+d] = sum_m aw1[p][k][m] * x[nbr[p][m]][d] ----
    {
        const int d = tid & 63, pg = tid >> 6;   // pg in 0..3
        for (int pi = 0; pi < 2; pi++) {
            const int p = pg + pi * 4;
            float xv[M];
            #pragma unroll
            for (int m = 0; m < M; m++) xv[m] = x[s_nbr[p][m] * D_IN + d];
            #pragma unroll
            for (int k = 0; k < KP; k++) {
                float acc = 0.f;
                #pragma unroll
                for (int m = 0; m < M; m++) acc += s_aw[p][k][m] * xv[m];
                s_wf[p][k * D_IN + d] = acc;
            }
        }
    }
    __syncthreads();

    // ---- phase 3: offset matmul  off[p][e] = sum_kd wf1[p][kd] * ow[kd][e] ----
    if (tid < 180) {
        const int e = tid % 45, h = tid / 45;    // h splits kd into 4x240
        float acc[P];
        #pragma unroll
        for (int p = 0; p < P; p++) acc[p] = 0.f;
        for (int i = 0; i < 240; i++) {
            const int kd = h * 240 + i;
            const float wv = ow[kd * E1 + e];
            #pragma unroll
            for (int p = 0; p < P; p++) acc[p] += s_wf[p][kd] * wv;
        }
        #pragma unroll
        for (int p = 0; p < P; p++) s_part[h][p][e] = acc[p];
    }
    __syncthreads();
    for (int idx = tid; idx < P * E1; idx += 256) {
        const int p = idx / E1, e = idx % E1;
        s_off[p][e] = s_part[0][p][e] + s_part[1][p][e] +
                      s_part[2][p][e] + s_part[3][p][e] + obias[e];
    }
    __syncthreads();

    // ---- phase 5: aw2 with deformed kernel points ----
    {
        const int p = tid >> 5, m = tid & 31;
        const float nbx = s_nb[p][m][0], nby = s_nb[p][m][1], nbz = s_nb[p][m][2];
        #pragma unroll
        for (int k = 0; k < KP; k++) {
            const float kx = s_kp[k][0] + s_off[p][k * 3 + 0];
            const float ky = s_kp[k][1] + s_off[p][k * 3 + 1];
            const float kz = s_kp[k][2] + s_off[p][k * 3 + 2];
            const float dx = nbx - kx, dy = nby - ky, dz = nbz - kz;
            const float d  = sqrtf(dx * dx + dy * dy + dz * dz);
            s_aw[p][k][m] = fmaxf(1.0f - d, 0.0f);
        }
    }
    __syncthreads();

    // ---- phase 6: wf2 (same structure as phase 2) ----
    {
        const int d = tid & 63, pg = tid >> 6;
        for (int pi = 0; pi < 2; pi++) {
            const int p = pg + pi * 4;
            float xv[M];
            #pragma unroll
            for (int m = 0; m < M; m++) xv[m] = x[s_nbr[p][m] * D_IN + d];
            #pragma unroll
            for (int k = 0; k < KP; k++) {
                float acc = 0.f;
                #pragma unroll
                for (int m = 0; m < M; m++) acc += s_aw[p][k][m] * xv[m];
                s_wf[p][k * D_IN + d] = acc;
            }
        }
    }
    __syncthreads();

    // ---- phase 7: output matmul  out[p][e] = sum_kd wf2[p][kd] * w[kd][e] ----
    {
        const int e = tid & 63, h = tid >> 6;
        float acc[P];
        #pragma unroll
        for (int p = 0; p < P; p++) acc[p] = 0.f;
        for (int i = 0; i < 240; i++) {
            const int kd = h * 240 + i;
            const float wv = w[kd * D_OUT + e];
            #pragma unroll
            for (int p = 0; p < P; p++) acc[p] += s_wf[p][kd] * wv;
        }
        #pragma unroll
        for (int p = 0; p < P; p++) s_part[h][p][e] = acc[p];
    }
    __syncthreads();
    for (int idx = tid; idx < P * D_OUT; idx += 256) {
        const int p = idx >> 6, e = idx & 63;
        out[(base + p) * D_OUT + e] =
            s_part[0][p][e] + s_part[1][p][e] + s_part[2][p][e] + s_part[3][p][e];
    }
}

extern "C" void kernel_launch(void* const* d_in, const int* in_sizes, int n_in,
                              void* d_out, int out_size, void* d_ws, size_t ws_size,
                              hipStream_t stream) {
    const float* q   = (const float*)d_in[0];
    const float* s   = (const float*)d_in[1];
    const int*   nb  = (const int*)  d_in[2];
    const float* x   = (const float*)d_in[3];
    const float* kp  = (const float*)d_in[4];
    const float* ow  = (const float*)d_in[5];
    const float* ob  = (const float*)d_in[6];
    const float* w   = (const float*)d_in[7];
    float* out = (float*)d_out;

    kpconv_deform<<<N_PTS / P, 256, 0, stream>>>(q, s, nb, x, kp, ow, ob, w, out);
}

// Round 2
// 709.013 us; speedup vs baseline: 1.1530x; 1.1530x over previous
//
#include <hip/hip_runtime.h>

#define N_PTS 50000
#define M 32
#define KP 15
#define D_IN 64
#define D_OUT 64
#define E1 45
#define P 8
#define KD (KP * D_IN)   // 960

// LDS budget: nbr 1K + nb 3K + wfT 30K + off 1.4K + buf(awT|part) 16K + misc ~= 53KB -> 3 blocks/CU
// s_awT[p][m][16]: aw broadcast operand as 4x uniform ds_read_b128 (was 15x b32)
// s_wfT[kd][8]: wf broadcast operand as 2x uniform ds_read_b128 (was 8x b32)
//   column permutation col(p) = ((p&3)<<1)|(p>>2) so wave w writes points {w, w+4}
//   as a single float2 (ds_write_b64) at cols {2w, 2w+1}; readers un-permute at
//   compile time: p(c) = ((c&1)<<2)|(c>>1).

__device__ __forceinline__ void wf_compute(
    const float (*s_awT)[M][16], const int (*s_nbr)[M],
    float (*s_wfT)[P], const float* __restrict__ x,
    int wid, int lane)
{
    float acc[2][KP];
    #pragma unroll
    for (int pi = 0; pi < 2; pi++) {
        const int p = wid + pi * 4;
        float xv[M];
        #pragma unroll
        for (int mm = 0; mm < M; mm++)
            xv[mm] = x[s_nbr[p][mm] * D_IN + lane];   // coalesced row gather
        #pragma unroll
        for (int k = 0; k < KP; k++) acc[pi][k] = 0.f;
        #pragma unroll
        for (int mm = 0; mm < M; mm++) {
            const float4* arow = (const float4*)s_awT[p][mm];
            const float4 a0 = arow[0], a1 = arow[1], a2 = arow[2], a3 = arow[3];
            const float xvm = xv[mm];
            acc[pi][0]  += a0.x * xvm; acc[pi][1]  += a0.y * xvm;
            acc[pi][2]  += a0.z * xvm; acc[pi][3]  += a0.w * xvm;
            acc[pi][4]  += a1.x * xvm; acc[pi][5]  += a1.y * xvm;
            acc[pi][6]  += a1.z * xvm; acc[pi][7]  += a1.w * xvm;
            acc[pi][8]  += a2.x * xvm; acc[pi][9]  += a2.y * xvm;
            acc[pi][10] += a2.z * xvm; acc[pi][11] += a2.w * xvm;
            acc[pi][12] += a3.x * xvm; acc[pi][13] += a3.y * xvm;
            acc[pi][14] += a3.z * xvm;
        }
    }
    #pragma unroll
    for (int k = 0; k < KP; k++) {
        const float2 v = make_float2(acc[0][k], acc[1][k]);
        *(float2*)&s_wfT[k * 64 + lane][2 * wid] = v;
    }
}

__global__ __launch_bounds__(256, 3) void kpconv_deform(
    const float* __restrict__ qpts,      // [N,3]
    const float* __restrict__ spts,      // [N,3]
    const int*   __restrict__ nbrs,      // [N,M]
    const float* __restrict__ x,         // [N,64]
    const float* __restrict__ kpts,      // [15,3]
    const float* __restrict__ ow,        // [15,64,45]
    const float* __restrict__ obias,     // [45]
    const float* __restrict__ w,         // [15,64,64]
    float* __restrict__ out)             // [N,64]
{
    __shared__ int   s_nbr[P][M];
    __shared__ float s_nb[P][M][3];
    __shared__ float s_kp[KP][3];
    __shared__ float s_q[P][3];
    __shared__ __align__(16) float s_wfT[KD][P];        // 30 KB
    __shared__ float s_off[P][E1];
    __shared__ __align__(16) float s_buf[P * M * 16];   // 16 KB, aliased:
    float (*s_awT)[M][16] = (float(*)[M][16])s_buf;     //   awT: ph1->ph2, ph5->ph6
    float (*s_part)[P][64] = (float(*)[P][64])s_buf;    //   part: ph3, ph7

    const int tid  = threadIdx.x;
    const int base = blockIdx.x * P;
    const int lane = tid & 63;
    const int wid  = tid >> 6;

    if (tid < KP * 3) ((float*)s_kp)[tid] = kpts[tid];
    if (tid < P * 3)  ((float*)s_q)[tid]  = qpts[base * 3 + tid];
    __syncthreads();

    // ---- ph1: gather neighbors, centered nb, aw1 -> s_awT ----
    {
        const int p = tid >> 5, m = tid & 31;
        const int nb_idx = nbrs[(base + p) * M + m];
        s_nbr[p][m] = nb_idx;
        const float nbx = spts[nb_idx * 3 + 0] - s_q[p][0];
        const float nby = spts[nb_idx * 3 + 1] - s_q[p][1];
        const float nbz = spts[nb_idx * 3 + 2] - s_q[p][2];
        s_nb[p][m][0] = nbx; s_nb[p][m][1] = nby; s_nb[p][m][2] = nbz;
        float awv[16];
        awv[15] = 0.f;
        #pragma unroll
        for (int k = 0; k < KP; k++) {
            const float dx = nbx - s_kp[k][0];
            const float dy = nby - s_kp[k][1];
            const float dz = nbz - s_kp[k][2];
            awv[k] = fmaxf(1.0f - sqrtf(dx * dx + dy * dy + dz * dz), 0.f);
        }
        float4* row = (float4*)s_awT[p][m];
        row[0] = make_float4(awv[0],  awv[1],  awv[2],  awv[3]);
        row[1] = make_float4(awv[4],  awv[5],  awv[6],  awv[7]);
        row[2] = make_float4(awv[8],  awv[9],  awv[10], awv[11]);
        row[3] = make_float4(awv[12], awv[13], awv[14], awv[15]);
    }
    __syncthreads();

    // ---- ph2: wf1 -> s_wfT (transposed, col-permuted) ----
    wf_compute(s_awT, s_nbr, s_wfT, x, wid, lane);
    __syncthreads();

    // ---- ph3: offset matmul, h-split over kd ----
    if (tid < 180) {
        const int e = tid % 45, h = tid / 45;
        float acc[8];
        #pragma unroll
        for (int c = 0; c < 8; c++) acc[c] = 0.f;
        const float* owp = ow + e;
        #pragma unroll 8
        for (int i = 0; i < 240; i++) {
            const int kd = h * 240 + i;
            const float wv = owp[kd * E1];
            const float4* row = (const float4*)s_wfT[kd];
            const float4 r0 = row[0], r1 = row[1];
            acc[0] += r0.x * wv; acc[1] += r0.y * wv;
            acc[2] += r0.z * wv; acc[3] += r0.w * wv;
            acc[4] += r1.x * wv; acc[5] += r1.y * wv;
            acc[6] += r1.z * wv; acc[7] += r1.w * wv;
        }
        #pragma unroll
        for (int c = 0; c < 8; c++) {
            const int p = ((c & 1) << 2) | (c >> 1);
            s_part[h][p][e] = acc[c];
        }
    }
    __syncthreads();

    // ---- reduce h-partials + bias -> offsets ----
    for (int idx = tid; idx < P * E1; idx += 256) {
        const int p = idx / E1, e = idx % E1;
        s_off[p][e] = s_part[0][p][e] + s_part[1][p][e] +
                      s_part[2][p][e] + s_part[3][p][e] + obias[e];
    }
    __syncthreads();

    // ---- ph5: aw2 with deformed kernel points -> s_awT ----
    {
        const int p = tid >> 5, m = tid & 31;
        const float nbx = s_nb[p][m][0], nby = s_nb[p][m][1], nbz = s_nb[p][m][2];
        float awv[16];
        awv[15] = 0.f;
        #pragma unroll
        for (int k = 0; k < KP; k++) {
            const float kx = s_kp[k][0] + s_off[p][k * 3 + 0];
            const float ky = s_kp[k][1] + s_off[p][k * 3 + 1];
            const float kz = s_kp[k][2] + s_off[p][k * 3 + 2];
            const float dx = nbx - kx, dy = nby - ky, dz = nbz - kz;
            awv[k] = fmaxf(1.0f - sqrtf(dx * dx + dy * dy + dz * dz), 0.f);
        }
        float4* row = (float4*)s_awT[p][m];
        row[0] = make_float4(awv[0],  awv[1],  awv[2],  awv[3]);
        row[1] = make_float4(awv[4],  awv[5],  awv[6],  awv[7]);
        row[2] = make_float4(awv[8],  awv[9],  awv[10], awv[11]);
        row[3] = make_float4(awv[12], awv[13], awv[14], awv[15]);
    }
    __syncthreads();

    // ---- ph6: wf2 -> s_wfT ----
    wf_compute(s_awT, s_nbr, s_wfT, x, wid, lane);
    __syncthreads();

    // ---- ph7: output matmul, h-split over kd ----
    {
        const int e = lane, h = wid;
        float acc[8];
        #pragma unroll
        for (int c = 0; c < 8; c++) acc[c] = 0.f;
        const float* wp = w + e;
        #pragma unroll 8
        for (int i = 0; i < 240; i++) {
            const int kd = h * 240 + i;
            const float wv = wp[kd * D_OUT];
            const float4* row = (const float4*)s_wfT[kd];
            const float4 r0 = row[0], r1 = row[1];
            acc[0] += r0.x * wv; acc[1] += r0.y * wv;
            acc[2] += r0.z * wv; acc[3] += r0.w * wv;
            acc[4] += r1.x * wv; acc[5] += r1.y * wv;
            acc[6] += r1.z * wv; acc[7] += r1.w * wv;
        }
        #pragma unroll
        for (int c = 0; c < 8; c++) {
            const int p = ((c & 1) << 2) | (c >> 1);
            s_part[h][p][e] = acc[c];
        }
    }
    __syncthreads();

    // ---- reduce + store ----
    #pragma unroll
    for (int idx = tid; idx < P * D_OUT; idx += 256) {
        const int p = idx >> 6, e = idx & 63;
        out[(base + p) * D_OUT + e] =
            s_part[0][p][e] + s_part[1][p][e] + s_part[2][p][e] + s_part[3][p][e];
    }
}

extern "C" void kernel_launch(void* const* d_in, const int* in_sizes, int n_in,
                              void* d_out, int out_size, void* d_ws, size_t ws_size,
                              hipStream_t stream) {
    const float* q   = (const float*)d_in[0];
    const float* s   = (const float*)d_in[1];
    const int*   nb  = (const int*)  d_in[2];
    const float* x   = (const float*)d_in[3];
    const float* kp  = (const float*)d_in[4];
    const float* ow  = (const float*)d_in[5];
    const float* ob  = (const float*)d_in[6];
    const float* w   = (const float*)d_in[7];
    float* out = (float*)d_out;

    kpconv_deform<<<N_PTS / P, 256, 0, stream>>>(q, s, nb, x, kp, ow, ob, w, out);
}

// Round 3
// 399.954 us; speedup vs baseline: 2.0439x; 1.7727x over previous
//
#include <hip/hip_runtime.h>

#define N_PTS 50000
#define M 32
#define KP 15
#define D 64
#define E1 45
#define P 8
#define KD_TOT (KP * D)   // 960

// Layouts chosen for LDS-bank behavior:
//  s_aw[p][k][m]  : writes (lane=m) 2-way conflict = free; reads wave-uniform b128
//  s_wf[p][kd]    : writes (lane=d) conflict-free; reads wave-uniform b128
// Sparsity: aw rows that are exactly all-zero (max(1-d,0)==0 for all m) are
// skipped EXACTLY via per-(p,k) ballot masks; union mask gates ph3/ph7 k-loops.

__device__ __forceinline__ void wf_phase(
    int p, unsigned pm, unsigned u, int lane,
    const int (*s_nbr)[M], const float (*s_aw)[KP][M],
    float (*s_wf)[KD_TOT], const float* __restrict__ x)
{
    float acc[KP];
#pragma unroll
    for (int k = 0; k < KP; k++) acc[k] = 0.f;
    if (pm) {
#pragma unroll
        for (int c = 0; c < M; c += 8) {          // m in chunks of 8: no spill
            float xv[8];
#pragma unroll
            for (int j = 0; j < 8; j++)
                xv[j] = x[s_nbr[p][c + j] * D + lane];   // coalesced 256B rows
#pragma unroll
            for (int k = 0; k < KP; k++) {
                if (!((pm >> k) & 1)) continue;   // wave-uniform skip
                const float4* a = (const float4*)&s_aw[p][k][c];
                const float4 a0 = a[0], a1 = a[1];
                acc[k] += a0.x * xv[0] + a0.y * xv[1] + a0.z * xv[2] + a0.w * xv[3]
                        + a1.x * xv[4] + a1.y * xv[5] + a1.z * xv[6] + a1.w * xv[7];
            }
        }
    }
#pragma unroll
    for (int k = 0; k < KP; k++)                  // zero-fill inactive union rows
        if ((u >> k) & 1) s_wf[p][k * D + lane] = acc[k];
}

__global__ __launch_bounds__(256, 3) void kpconv_deform(
    const float* __restrict__ qpts,      // [N,3]
    const float* __restrict__ spts,      // [N,3]
    const int*   __restrict__ nbrs,      // [N,M]
    const float* __restrict__ x,         // [N,64]
    const float* __restrict__ kpts,      // [15,3]
    const float* __restrict__ ow,        // [15,64,45]
    const float* __restrict__ obias,     // [45]
    const float* __restrict__ w,         // [15,64,64]
    float* __restrict__ out)             // [N,64]
{
    __shared__ int   s_nbr[P][M];
    __shared__ float s_nb[P][M][3];
    __shared__ float s_kp[KP][3];
    __shared__ float s_q[P][3];
    __shared__ __align__(16) float s_wf[P][KD_TOT];   // 30 KB
    __shared__ float s_off[P][E1];
    __shared__ unsigned s_act[P];
    __shared__ __align__(16) float s_aw[P][KP][M];    // 15 KB; aliased:
    float (*s_part)[P][64] = (float(*)[P][64])s_aw;   // [4][8][64]=8KB, lifetimes disjoint

    const int tid  = threadIdx.x;
    const int base = blockIdx.x * P;
    const int lane = tid & 63;
    const int wid  = tid >> 6;

    if (tid < KP * 3) ((float*)s_kp)[tid] = kpts[tid];
    if (tid < P * 3)  ((float*)s_q)[tid]  = qpts[base * 3 + tid];
    __syncthreads();

    // ---- ph1: gather neighbors, centered nb, aw1 + activity masks ----
    {
        const int p = tid >> 5, m = tid & 31;
        const int ni = nbrs[(base + p) * M + m];
        s_nbr[p][m] = ni;
        const float nbx = spts[ni * 3 + 0] - s_q[p][0];
        const float nby = spts[ni * 3 + 1] - s_q[p][1];
        const float nbz = spts[ni * 3 + 2] - s_q[p][2];
        s_nb[p][m][0] = nbx; s_nb[p][m][1] = nby; s_nb[p][m][2] = nbz;
        unsigned pmask = 0;
#pragma unroll
        for (int k = 0; k < KP; k++) {
            const float dx = nbx - s_kp[k][0];
            const float dy = nby - s_kp[k][1];
            const float dz = nbz - s_kp[k][2];
            const float av = fmaxf(1.0f - sqrtf(dx * dx + dy * dy + dz * dz), 0.f);
            s_aw[p][k][m] = av;
            const unsigned long long b = __ballot(av > 0.f);
            const unsigned any = (tid & 32) ? (unsigned)(b >> 32) : (unsigned)b;
            pmask |= (any ? 1u : 0u) << k;
        }
        if ((tid & 31) == 0) s_act[p] = pmask;
    }
    __syncthreads();

    const unsigned u1 = s_act[0] | s_act[1] | s_act[2] | s_act[3] |
                        s_act[4] | s_act[5] | s_act[6] | s_act[7];

    // ---- ph2: wf1 (two points per wave, sequential) ----
    wf_phase(2 * wid + 0, s_act[2 * wid + 0], u1, lane, s_nbr, s_aw, s_wf, x);
    wf_phase(2 * wid + 1, s_act[2 * wid + 1], u1, lane, s_nbr, s_aw, s_wf, x);
    __syncthreads();

    // ---- ph3: offset matmul over active union k ----
    {
        float acc[P];
#pragma unroll
        for (int p = 0; p < P; p++) acc[p] = 0.f;
        if (lane < E1) {
#pragma unroll
            for (int k = 0; k < KP; k++) {
                if (!((u1 >> k) & 1)) continue;
#pragma unroll
                for (int c = 0; c < 4; c++) {
                    const int kd0 = k * D + wid * 16 + c * 4;
                    const float w0 = ow[(kd0 + 0) * E1 + lane];
                    const float w1 = ow[(kd0 + 1) * E1 + lane];
                    const float w2 = ow[(kd0 + 2) * E1 + lane];
                    const float w3 = ow[(kd0 + 3) * E1 + lane];
#pragma unroll
                    for (int p = 0; p < P; p++) {
                        const float4 f = *(const float4*)&s_wf[p][kd0];
                        acc[p] += f.x * w0 + f.y * w1 + f.z * w2 + f.w * w3;
                    }
                }
            }
        }
#pragma unroll
        for (int p = 0; p < P; p++) s_part[wid][p][lane] = acc[p];
    }
    __syncthreads();

    // ---- reduce partials + bias -> offsets ----
    for (int idx = tid; idx < P * E1; idx += 256) {
        const int p = idx / E1, e = idx % E1;
        s_off[p][e] = s_part[0][p][e] + s_part[1][p][e] +
                      s_part[2][p][e] + s_part[3][p][e] + obias[e];
    }
    __syncthreads();

    // ---- ph5: aw2 with deformed kernel points + activity masks ----
    {
        const int p = tid >> 5, m = tid & 31;
        const float nbx = s_nb[p][m][0], nby = s_nb[p][m][1], nbz = s_nb[p][m][2];
        unsigned pmask = 0;
#pragma unroll
        for (int k = 0; k < KP; k++) {
            const float kx = s_kp[k][0] + s_off[p][3 * k + 0];
            const float ky = s_kp[k][1] + s_off[p][3 * k + 1];
            const float kz = s_kp[k][2] + s_off[p][3 * k + 2];
            const float dx = nbx - kx, dy = nby - ky, dz = nbz - kz;
            const float av = fmaxf(1.0f - sqrtf(dx * dx + dy * dy + dz * dz), 0.f);
            s_aw[p][k][m] = av;
            const unsigned long long b = __ballot(av > 0.f);
            const unsigned any = (tid & 32) ? (unsigned)(b >> 32) : (unsigned)b;
            pmask |= (any ? 1u : 0u) << k;
        }
        if ((tid & 31) == 0) s_act[p] = pmask;
    }
    __syncthreads();

    const unsigned u2 = s_act[0] | s_act[1] | s_act[2] | s_act[3] |
                        s_act[4] | s_act[5] | s_act[6] | s_act[7];

    // ---- ph6: wf2 (expected ~95% of k-rows exactly zero -> skipped) ----
    wf_phase(2 * wid + 0, s_act[2 * wid + 0], u2, lane, s_nbr, s_aw, s_wf, x);
    wf_phase(2 * wid + 1, s_act[2 * wid + 1], u2, lane, s_nbr, s_aw, s_wf, x);
    __syncthreads();

    // ---- ph7: output matmul over active union k ----
    {
        float acc[P];
#pragma unroll
        for (int p = 0; p < P; p++) acc[p] = 0.f;
#pragma unroll
        for (int k = 0; k < KP; k++) {
            if (!((u2 >> k) & 1)) continue;
#pragma unroll
            for (int c = 0; c < 4; c++) {
                const int kd0 = k * D + wid * 16 + c * 4;
                const float w0 = w[(kd0 + 0) * D + lane];
                const float w1 = w[(kd0 + 1) * D + lane];
                const float w2 = w[(kd0 + 2) * D + lane];
                const float w3 = w[(kd0 + 3) * D + lane];
#pragma unroll
                for (int p = 0; p < P; p++) {
                    const float4 f = *(const float4*)&s_wf[p][kd0];
                    acc[p] += f.x * w0 + f.y * w1 + f.z * w2 + f.w * w3;
                }
            }
        }
#pragma unroll
        for (int p = 0; p < P; p++) s_part[wid][p][lane] = acc[p];
    }
    __syncthreads();

    // ---- reduce + store ----
#pragma unroll
    for (int idx = tid; idx < P * D; idx += 256) {
        const int p = idx >> 6, e = idx & 63;
        out[(base + p) * D + e] =
            s_part[0][p][e] + s_part[1][p][e] + s_part[2][p][e] + s_part[3][p][e];
    }
}

extern "C" void kernel_launch(void* const* d_in, const int* in_sizes, int n_in,
                              void* d_out, int out_size, void* d_ws, size_t ws_size,
                              hipStream_t stream) {
    const float* q   = (const float*)d_in[0];
    const float* s   = (const float*)d_in[1];
    const int*   nb  = (const int*)  d_in[2];
    const float* x   = (const float*)d_in[3];
    const float* kp  = (const float*)d_in[4];
    const float* ow  = (const float*)d_in[5];
    const float* ob  = (const float*)d_in[6];
    const float* w   = (const float*)d_in[7];
    float* out = (float*)d_out;

    kpconv_deform<<<N_PTS / P, 256, 0, stream>>>(q, s, nb, x, kp, ow, ob, w, out);
}

// Round 7
// 258.941 us; speedup vs baseline: 3.1570x; 1.5446x over previous
//
#include <hip/hip_runtime.h>

#define N_PTS 50000
#define M 32
#define KP 15
#define D 64
#define E1 45
#define P 8
#define WFS 1036   // s_wf row stride (floats): >=1024 enum slots; 1036%32=12 breaks pr-conflicts

typedef __attribute__((ext_vector_type(8))) short bf16x8;
typedef __attribute__((ext_vector_type(4))) float f32x4;

__device__ __forceinline__ short f2bf(float f) {          // RNE fp32->bf16
    unsigned u = __float_as_uint(f);
    return (short)((u + 0x7fffu + ((u >> 16) & 1u)) >> 16);
}
__device__ __forceinline__ float bf2f(short h) {
    return __uint_as_float(((unsigned)(unsigned short)h) << 16);
}
// packed two-term bf16 split: lo16 bits = hi term, hi16 bits = lo term; v ~= hi+lo
__device__ __forceinline__ unsigned splitpack(float v) {
    const short h = f2bf(v);
    const short l = f2bf(v - bf2f(h));
    return (unsigned)(unsigned short)h | ((unsigned)(unsigned short)l << 16);
}
__device__ __forceinline__ void unpack8(const uint4& u0, const uint4& u1,
                                        bf16x8& h, bf16x8& l) {
    h[0] = (short)u0.x; l[0] = (short)(u0.x >> 16);
    h[1] = (short)u0.y; l[1] = (short)(u0.y >> 16);
    h[2] = (short)u0.z; l[2] = (short)(u0.z >> 16);
    h[3] = (short)u0.w; l[3] = (short)(u0.w >> 16);
    h[4] = (short)u1.x; l[4] = (short)(u1.x >> 16);
    h[5] = (short)u1.y; l[5] = (short)(u1.y >> 16);
    h[6] = (short)u1.z; l[6] = (short)(u1.z >> 16);
    h[7] = (short)u1.w; l[7] = (short)(u1.w >> 16);
}

// ---------------- prep kernels (write into d_ws; ~13 MB total) --------------
__global__ void prep_x_split(const float* __restrict__ x, unsigned* __restrict__ xw) {
    const int i = blockIdx.x * 256 + threadIdx.x;          // 3,200,000 = 12500*256
    xw[i] = splitpack(x[i]);
}

// oww: [ks(32)][nt(3)][lane(64)][8]; contraction enum i = d*16 + k16,
// zeros at k==15 / e>=45 contribute exactly 0.
__global__ void prep_ow_split(const float* __restrict__ ow, unsigned* __restrict__ oww) {
    const int t = blockIdx.x * 256 + threadIdx.x;          // 49152 = 192*256
    const int j = t & 7, lane = (t >> 3) & 63, rest = t >> 9;
    const int nt = rest % 3, ks = rest / 3;
    const int q = lane >> 4, c = lane & 15;
    const int i = ks * 32 + q * 8 + j, d = i >> 4, k = i & 15, e = nt * 16 + c;
    const float v = (k < KP && e < E1) ? ow[k * (D * E1) + d * E1 + e] : 0.f;
    oww[t] = splitpack(v);
}

// ---------------- sparse fp32 wf (ph6) --------------------------------------
__device__ __forceinline__ void wf_phase(
    int p, unsigned pm, unsigned u, int lane,
    const int (*s_nbr)[M], const float (*s_aw)[KP][M],
    float (*s_wf)[WFS], const float* __restrict__ x)
{
    float acc[KP];
#pragma unroll
    for (int k = 0; k < KP; k++) acc[k] = 0.f;
    if (pm) {
#pragma unroll
        for (int c = 0; c < M; c += 8) {
            float xv[8];
#pragma unroll
            for (int j = 0; j < 8; j++)
                xv[j] = x[s_nbr[p][c + j] * D + lane];
#pragma unroll
            for (int k = 0; k < KP; k++) {
                if (!((pm >> k) & 1)) continue;
                const float4* a = (const float4*)&s_aw[p][k][c];
                const float4 a0 = a[0], a1 = a[1];
                acc[k] += a0.x * xv[0] + a0.y * xv[1] + a0.z * xv[2] + a0.w * xv[3]
                        + a1.x * xv[4] + a1.y * xv[5] + a1.z * xv[6] + a1.w * xv[7];
            }
        }
    }
#pragma unroll
    for (int k = 0; k < KP; k++)
        if ((u >> k) & 1) s_wf[p][k * D + lane] = acc[k];
}

__global__ __launch_bounds__(256, 3) void kpconv_deform(
    const float* __restrict__ qpts, const float* __restrict__ spts,
    const int*   __restrict__ nbrs, const float* __restrict__ x,
    const float* __restrict__ kpts, const float* __restrict__ obias,
    const float* __restrict__ w,
    const unsigned* __restrict__ xw,    // packed split-bf16 x
    const unsigned* __restrict__ oww,   // packed split-bf16 ow (frag order)
    float* __restrict__ out)
{
    __shared__ int   s_nbr[P][M];
    __shared__ float s_kp[KP][3];
    __shared__ float s_q[P][3];
    __shared__ float s_off[P][E1];
    __shared__ unsigned s_act[P];
    // bufA (33152 B): wf fp32. ph2->ph3 enum [p][d*16+k16]; ph6->ph7 enum [p][k*64+d]
    __shared__ __align__(16) char s_bufA[P * WFS * 4];
    float (*s_wf)[WFS] = (float(*)[WFS])s_bufA;
    // bufB (16384 B): awu packed (ph1->ph2) | ph3 partials | aw fp32 (ph5->ph6) | ph7 partials
    __shared__ __align__(16) char s_bufB[P * 512 * 4];
    unsigned (*s_awu)[512]   = (unsigned(*)[512])s_bufB;   // [p][k16*32+m] packed
    float (*s_aw)[KP][M]     = (float(*)[KP][M])s_bufB;
    float (*s_part3)[16][49] = (float(*)[16][49])s_bufB;   // ph3: 12544 B
    float (*s_part7)[P][64]  = (float(*)[P][64])s_bufB;    // ph7:  8192 B

    const int tid  = threadIdx.x;
    const int base = blockIdx.x * P;
    const int lane = tid & 63;
    const int wid  = tid >> 6;
    const int q    = lane >> 4, c = lane & 15;
    const int pg   = tid >> 5, mg = tid & 31;   // (p,m) mapping for ph1/ph5

    // centered neighbor coords: live in registers from ph1 to ph5 (same thread mapping)
    float nbx, nby, nbz;

    if (tid < KP * 3) ((float*)s_kp)[tid] = kpts[tid];
    if (tid < P * 3)  ((float*)s_q)[tid]  = qpts[base * 3 + tid];
    __syncthreads();

    // ---- ph1: gather, centered nb, aw1 -> packed split-bf16 A operand ----
    {
        const int ni = nbrs[(base + pg) * M + mg];
        s_nbr[pg][mg] = ni;
        nbx = spts[ni * 3 + 0] - s_q[pg][0];
        nby = spts[ni * 3 + 1] - s_q[pg][1];
        nbz = spts[ni * 3 + 2] - s_q[pg][2];
#pragma unroll
        for (int k = 0; k < KP; k++) {
            const float dx = nbx - s_kp[k][0];
            const float dy = nby - s_kp[k][1];
            const float dz = nbz - s_kp[k][2];
            const float av = fmaxf(1.0f - sqrtf(dx * dx + dy * dy + dz * dz), 0.f);
            s_awu[pg][k * 32 + mg] = splitpack(av);
        }
        s_awu[pg][15 * 32 + mg] = 0;                 // pad row -> exact zeros
    }
    __syncthreads();

    // ---- ph2: wf1 via compensated MFMA: D[k16][d16] = aw[k16][m32]*xg[m32][d16] ----
    {
#pragma unroll
        for (int pi = 0; pi < 2; pi++) {
            const int p = 2 * wid + pi;
            const uint4 au0 = *(const uint4*)&s_awu[p][(lane & 15) * 32 + q * 8];
            const uint4 au1 = *(const uint4*)&s_awu[p][(lane & 15) * 32 + q * 8 + 4];
            bf16x8 ah, al; unpack8(au0, au1, ah, al);
            int nbj[8];
#pragma unroll
            for (int j = 0; j < 8; j++) nbj[j] = s_nbr[p][q * 8 + j];
#pragma unroll
            for (int t = 0; t < 4; t++) {
                unsigned g[8];
#pragma unroll
                for (int j = 0; j < 8; j++)
                    g[j] = xw[nbj[j] * D + t * 16 + c];
                bf16x8 bh, bl;
#pragma unroll
                for (int j = 0; j < 8; j++) {
                    bh[j] = (short)g[j]; bl[j] = (short)(g[j] >> 16);
                }
                f32x4 dacc = {0.f, 0.f, 0.f, 0.f};
                dacc = __builtin_amdgcn_mfma_f32_16x16x32_bf16(ah, bh, dacc, 0, 0, 0);
                dacc = __builtin_amdgcn_mfma_f32_16x16x32_bf16(ah, bl, dacc, 0, 0, 0);
                dacc = __builtin_amdgcn_mfma_f32_16x16x32_bf16(al, bh, dacc, 0, 0, 0);
                // rows k=4q+r (consecutive), col d=16t+c -> enum [p][d*16+k], fp32
                *(f32x4*)&s_wf[p][(t * 16 + c) * 16 + 4 * q] = dacc;   // max idx 1023 < WFS
            }
        }
    }
    __syncthreads();

    // ---- ph3: offsets via compensated MFMA, contraction split over 4 waves ----
    {
        const int pr = lane & 7;                     // A rows 8..15 duplicate points 0..7
        f32x4 acc0 = {0,0,0,0}, acc1 = {0,0,0,0}, acc2 = {0,0,0,0};
        const uint4* bp = (const uint4*)oww;
#pragma unroll
        for (int s = 0; s < 8; s++) {
            const int ks = wid * 8 + s;
            const float4 f0 = *(const float4*)&s_wf[pr][ks * 32 + q * 8];
            const float4 f1 = *(const float4*)&s_wf[pr][ks * 32 + q * 8 + 4];
            float av[8] = {f0.x, f0.y, f0.z, f0.w, f1.x, f1.y, f1.z, f1.w};
            bf16x8 ah, al;
#pragma unroll
            for (int j = 0; j < 8; j++) {
                const short h = f2bf(av[j]);
                ah[j] = h; al[j] = f2bf(av[j] - bf2f(h));
            }
#pragma unroll
            for (int nt = 0; nt < 3; nt++) {
                const uint4 b0 = bp[((ks * 3 + nt) * 64 + lane) * 2 + 0];
                const uint4 b1 = bp[((ks * 3 + nt) * 64 + lane) * 2 + 1];
                bf16x8 bh, bl; unpack8(b0, b1, bh, bl);
                f32x4* acc = (nt == 0) ? &acc0 : (nt == 1) ? &acc1 : &acc2;
                *acc = __builtin_amdgcn_mfma_f32_16x16x32_bf16(ah, bh, *acc, 0, 0, 0);
                *acc = __builtin_amdgcn_mfma_f32_16x16x32_bf16(ah, bl, *acc, 0, 0, 0);
                *acc = __builtin_amdgcn_mfma_f32_16x16x32_bf16(al, bh, *acc, 0, 0, 0);
            }
        }
#pragma unroll
        for (int r = 0; r < 4; r++) {
            s_part3[wid][4 * q + r][0 * 16 + c] = acc0[r];
            s_part3[wid][4 * q + r][1 * 16 + c] = acc1[r];
            s_part3[wid][4 * q + r][2 * 16 + c] = acc2[r];
        }
    }
    __syncthreads();

    // ---- reduce K-partials + bias -> offsets (fp32) ----
    for (int idx = tid; idx < P * E1; idx += 256) {
        const int p = idx / E1, e = idx % E1;
        s_off[p][e] = s_part3[0][p][e] + s_part3[1][p][e] +
                      s_part3[2][p][e] + s_part3[3][p][e] + obias[e];
    }
    __syncthreads();

    // ---- ph5: aw2 with deformed kernel points (fp32) + activity masks ----
    {
        unsigned pmask = 0;
#pragma unroll
        for (int k = 0; k < KP; k++) {
            const float kx = s_kp[k][0] + s_off[pg][3 * k + 0];
            const float ky = s_kp[k][1] + s_off[pg][3 * k + 1];
            const float kz = s_kp[k][2] + s_off[pg][3 * k + 2];
            const float dx = nbx - kx, dy = nby - ky, dz = nbz - kz;
            const float av = fmaxf(1.0f - sqrtf(dx * dx + dy * dy + dz * dz), 0.f);
            s_aw[pg][k][mg] = av;
            const unsigned long long b = __ballot(av > 0.f);
            const unsigned any = (tid & 32) ? (unsigned)(b >> 32) : (unsigned)b;
            pmask |= (any ? 1u : 0u) << k;
        }
        if ((tid & 31) == 0) s_act[pg] = pmask;
    }
    __syncthreads();

    const unsigned u2 = s_act[0] | s_act[1] | s_act[2] | s_act[3] |
                        s_act[4] | s_act[5] | s_act[6] | s_act[7];

    // ---- ph6: wf2 (mostly exactly-zero rows -> skipped) ----
    wf_phase(2 * wid + 0, s_act[2 * wid + 0], u2, lane, s_nbr, s_aw, s_wf, x);
    wf_phase(2 * wid + 1, s_act[2 * wid + 1], u2, lane, s_nbr, s_aw, s_wf, x);
    __syncthreads();

    // ---- ph7: output matmul over active union k (fp32) ----
    {
        float acc[P];
#pragma unroll
        for (int p = 0; p < P; p++) acc[p] = 0.f;
#pragma unroll
        for (int k = 0; k < KP; k++) {
            if (!((u2 >> k) & 1)) continue;
#pragma unroll
            for (int cc = 0; cc < 4; cc++) {
                const int kd0 = k * D + wid * 16 + cc * 4;
                const float w0 = w[(kd0 + 0) * D + lane];
                const float w1 = w[(kd0 + 1) * D + lane];
                const float w2 = w[(kd0 + 2) * D + lane];
                const float w3 = w[(kd0 + 3) * D + lane];
#pragma unroll
                for (int p = 0; p < P; p++) {
                    const float4 f = *(const float4*)&s_wf[p][kd0];
                    acc[p] += f.x * w0 + f.y * w1 + f.z * w2 + f.w * w3;
                }
            }
        }
#pragma unroll
        for (int p = 0; p < P; p++) s_part7[wid][p][lane] = acc[p];
    }
    __syncthreads();

    for (int idx = tid; idx < P * D; idx += 256) {
        const int p = idx >> 6, e = idx & 63;
        out[(base + p) * D + e] =
            s_part7[0][p][e] + s_part7[1][p][e] + s_part7[2][p][e] + s_part7[3][p][e];
    }
}

extern "C" void kernel_launch(void* const* d_in, const int* in_sizes, int n_in,
                              void* d_out, int out_size, void* d_ws, size_t ws_size,
                              hipStream_t stream) {
    const float* q   = (const float*)d_in[0];
    const float* s   = (const float*)d_in[1];
    const int*   nb  = (const int*)  d_in[2];
    const float* x   = (const float*)d_in[3];
    const float* kp  = (const float*)d_in[4];
    const float* ow  = (const float*)d_in[5];
    const float* ob  = (const float*)d_in[6];
    const float* w   = (const float*)d_in[7];
    float* out = (float*)d_out;

    unsigned* xw  = (unsigned*)d_ws;                        // 12,800,000 B
    unsigned* oww = (unsigned*)((char*)d_ws + 12800000);    //    196,608 B

    prep_x_split <<<N_PTS * D / 256, 256, 0, stream>>>(x, xw);
    prep_ow_split<<<192,             256, 0, stream>>>(ow, oww);
    kpconv_deform<<<N_PTS / P, 256, 0, stream>>>(q, s, nb, x, kp, ob, w, xw, oww, out);
}

// Round 8
// 243.215 us; speedup vs baseline: 3.3611x; 1.0647x over previous
//
#include <hip/hip_runtime.h>

#define N_PTS 50000
#define M 32
#define KP 15
#define D 64
#define E1 45
#define P 8
#define WFS 1036   // s_wf row stride (uints): >=1024 enum slots (ph2/ph3); ph6/ph7 use 960

typedef __attribute__((ext_vector_type(8))) short bf16x8;
typedef __attribute__((ext_vector_type(4))) float f32x4;

__device__ __forceinline__ short f2bf(float f) {          // RNE fp32->bf16
    unsigned u = __float_as_uint(f);
    return (short)((u + 0x7fffu + ((u >> 16) & 1u)) >> 16);
}
__device__ __forceinline__ float bf2f(short h) {
    return __uint_as_float(((unsigned)(unsigned short)h) << 16);
}
// packed two-term bf16 split: lo16 bits = hi term, hi16 bits = lo term; v ~= hi+lo
__device__ __forceinline__ unsigned splitpack(float v) {
    const short h = f2bf(v);
    const short l = f2bf(v - bf2f(h));
    return (unsigned)(unsigned short)h | ((unsigned)(unsigned short)l << 16);
}
__device__ __forceinline__ void unpack8(const uint4& u0, const uint4& u1,
                                        bf16x8& h, bf16x8& l) {
    h[0] = (short)u0.x; l[0] = (short)(u0.x >> 16);
    h[1] = (short)u0.y; l[1] = (short)(u0.y >> 16);
    h[2] = (short)u0.z; l[2] = (short)(u0.z >> 16);
    h[3] = (short)u0.w; l[3] = (short)(u0.w >> 16);
    h[4] = (short)u1.x; l[4] = (short)(u1.x >> 16);
    h[5] = (short)u1.y; l[5] = (short)(u1.y >> 16);
    h[6] = (short)u1.z; l[6] = (short)(u1.z >> 16);
    h[7] = (short)u1.w; l[7] = (short)(u1.w >> 16);
}

// ---------------- fused prep kernel (one launch; writes d_ws) ----------------
// blocks [0,12500): x -> packed split      (3,200,000 vals)
// blocks [12500,12692): ow -> frag layout  [ks32][nt3][lane64][j8], enum i=d*16+k16
// blocks [12692,12932): w  -> frag layout  [ks30][nt4][lane64][j8], enum kc=k*64+d
__global__ void prep_all(const float* __restrict__ x, const float* __restrict__ ow,
                         const float* __restrict__ w, unsigned* __restrict__ xw,
                         unsigned* __restrict__ oww, unsigned* __restrict__ ww7)
{
    const int b = blockIdx.x, tid = threadIdx.x;
    if (b < 12500) {
        const int i = b * 256 + tid;
        xw[i] = splitpack(x[i]);
    } else if (b < 12692) {
        const int t = (b - 12500) * 256 + tid;              // [0, 49152)
        const int j = t & 7, lane = (t >> 3) & 63, rest = t >> 9;
        const int nt = rest % 3, ks = rest / 3;
        const int q = lane >> 4, c = lane & 15;
        const int i = ks * 32 + q * 8 + j, d = i >> 4, k = i & 15, e = nt * 16 + c;
        const float v = (k < KP && e < E1) ? ow[k * (D * E1) + d * E1 + e] : 0.f;
        oww[t] = splitpack(v);
    } else {
        const int t = (b - 12692) * 256 + tid;              // [0, 61440)
        const int j = t & 7, lane = (t >> 3) & 63, rest = t >> 9;
        const int nt = rest & 3, ks = rest >> 2;            // ks in [0,30)
        const int q = lane >> 4, c = lane & 15;
        const int kc = ks * 32 + q * 8 + j, e = nt * 16 + c;
        ww7[t] = splitpack(w[kc * D + e]);
    }
}

// ---------------- sparse fp32 wf (ph6) -> packed split-bf16 ------------------
__device__ __forceinline__ void wf_phase(
    int p, unsigned pm, unsigned u, int lane,
    const int (*s_nbr)[M], const float (*s_aw)[KP][M],
    unsigned (*s_wfu)[WFS], const float* __restrict__ x)
{
    float acc[KP];
#pragma unroll
    for (int k = 0; k < KP; k++) acc[k] = 0.f;
    if (pm) {
#pragma unroll
        for (int c = 0; c < M; c += 8) {
            float xv[8];
#pragma unroll
            for (int j = 0; j < 8; j++)
                xv[j] = x[s_nbr[p][c + j] * D + lane];
#pragma unroll
            for (int k = 0; k < KP; k++) {
                if (!((pm >> k) & 1)) continue;
                const float4* a = (const float4*)&s_aw[p][k][c];
                const float4 a0 = a[0], a1 = a[1];
                acc[k] += a0.x * xv[0] + a0.y * xv[1] + a0.z * xv[2] + a0.w * xv[3]
                        + a1.x * xv[4] + a1.y * xv[5] + a1.z * xv[6] + a1.w * xv[7];
            }
        }
    }
#pragma unroll
    for (int k = 0; k < KP; k++)                 // enum [p][k*64+d] for ph7
        if ((u >> k) & 1) s_wfu[p][k * D + lane] = splitpack(acc[k]);
}

__global__ __launch_bounds__(256, 3) void kpconv_deform(
    const float* __restrict__ qpts, const float* __restrict__ spts,
    const int*   __restrict__ nbrs, const float* __restrict__ x,
    const float* __restrict__ kpts, const float* __restrict__ obias,
    const unsigned* __restrict__ xw,    // packed split-bf16 x
    const unsigned* __restrict__ oww,   // packed split-bf16 ow (frag order)
    const unsigned* __restrict__ ww7,   // packed split-bf16 w  (frag order)
    float* __restrict__ out)
{
    __shared__ int   s_nbr[P][M];
    __shared__ float s_kp[KP][3];
    __shared__ float s_q[P][3];
    __shared__ float s_off[P][E1];
    __shared__ unsigned s_act[P];
    // bufA (33152 B): wf packed split. ph2->ph3 enum [p][d*16+k16]; ph6->ph7 [p][k*64+d]
    __shared__ __align__(16) unsigned s_wfu[P][WFS];
    // bufB (16384 B): awu packed (ph1->ph2) | ph3 partials | aw fp32 (ph5->ph6)
    __shared__ __align__(16) char s_bufB[P * 512 * 4];
    unsigned (*s_awu)[512]   = (unsigned(*)[512])s_bufB;   // [p][k16*32+m] packed
    float (*s_aw)[KP][M]     = (float(*)[KP][M])s_bufB;
    float (*s_part3)[16][49] = (float(*)[16][49])s_bufB;   // ph3: 12544 B

    const int tid  = threadIdx.x;
    const int base = blockIdx.x * P;
    const int lane = tid & 63;
    const int wid  = tid >> 6;
    const int q    = lane >> 4, c = lane & 15;
    const int pg   = tid >> 5, mg = tid & 31;   // (p,m) mapping for ph1/ph5

    float nbx, nby, nbz;   // centered neighbor coords, live ph1->ph5

    if (tid < KP * 3) ((float*)s_kp)[tid] = kpts[tid];
    if (tid < P * 3)  ((float*)s_q)[tid]  = qpts[base * 3 + tid];
    __syncthreads();

    // ---- ph1: gather, centered nb, aw1 -> packed split-bf16 A operand ----
    {
        const int ni = nbrs[(base + pg) * M + mg];
        s_nbr[pg][mg] = ni;
        nbx = spts[ni * 3 + 0] - s_q[pg][0];
        nby = spts[ni * 3 + 1] - s_q[pg][1];
        nbz = spts[ni * 3 + 2] - s_q[pg][2];
#pragma unroll
        for (int k = 0; k < KP; k++) {
            const float dx = nbx - s_kp[k][0];
            const float dy = nby - s_kp[k][1];
            const float dz = nbz - s_kp[k][2];
            const float av = fmaxf(1.0f - sqrtf(dx * dx + dy * dy + dz * dz), 0.f);
            s_awu[pg][k * 32 + mg] = splitpack(av);
        }
        s_awu[pg][15 * 32 + mg] = 0;                 // pad row -> exact zeros
    }
    __syncthreads();

    // ---- ph2: wf1 via compensated MFMA: D[k16][d16] = aw[k16][m32]*xg[m32][d16] ----
    {
#pragma unroll
        for (int pi = 0; pi < 2; pi++) {
            const int p = 2 * wid + pi;
            const uint4 au0 = *(const uint4*)&s_awu[p][(lane & 15) * 32 + q * 8];
            const uint4 au1 = *(const uint4*)&s_awu[p][(lane & 15) * 32 + q * 8 + 4];
            bf16x8 ah, al; unpack8(au0, au1, ah, al);
            int nbj[8];
#pragma unroll
            for (int j = 0; j < 8; j++) nbj[j] = s_nbr[p][q * 8 + j];
#pragma unroll
            for (int t = 0; t < 4; t++) {
                unsigned g[8];
#pragma unroll
                for (int j = 0; j < 8; j++)
                    g[j] = xw[nbj[j] * D + t * 16 + c];
                bf16x8 bh, bl;
#pragma unroll
                for (int j = 0; j < 8; j++) {
                    bh[j] = (short)g[j]; bl[j] = (short)(g[j] >> 16);
                }
                f32x4 dacc = {0.f, 0.f, 0.f, 0.f};
                dacc = __builtin_amdgcn_mfma_f32_16x16x32_bf16(ah, bh, dacc, 0, 0, 0);
                dacc = __builtin_amdgcn_mfma_f32_16x16x32_bf16(ah, bl, dacc, 0, 0, 0);
                dacc = __builtin_amdgcn_mfma_f32_16x16x32_bf16(al, bh, dacc, 0, 0, 0);
                // rows k=4q+r, col d=16t+c -> enum [p][d*16+k], packed split-bf16
                uint4 pk;
                pk.x = splitpack(dacc[0]); pk.y = splitpack(dacc[1]);
                pk.z = splitpack(dacc[2]); pk.w = splitpack(dacc[3]);
                *(uint4*)&s_wfu[p][(t * 16 + c) * 16 + 4 * q] = pk;   // max idx 1023
            }
        }
    }
    __syncthreads();

    // ---- ph3: offsets via compensated MFMA, contraction split over 4 waves ----
    {
        const int pr = lane & 7;                     // A rows 8..15 duplicate points 0..7
        f32x4 acc0 = {0,0,0,0}, acc1 = {0,0,0,0}, acc2 = {0,0,0,0};
        const uint4* bp = (const uint4*)oww;
#pragma unroll
        for (int s = 0; s < 8; s++) {
            const int ks = wid * 8 + s;
            const uint4 a0 = *(const uint4*)&s_wfu[pr][ks * 32 + q * 8];
            const uint4 a1 = *(const uint4*)&s_wfu[pr][ks * 32 + q * 8 + 4];
            bf16x8 ah, al; unpack8(a0, a1, ah, al);
#pragma unroll
            for (int nt = 0; nt < 3; nt++) {
                const uint4 b0 = bp[((ks * 3 + nt) * 64 + lane) * 2 + 0];
                const uint4 b1 = bp[((ks * 3 + nt) * 64 + lane) * 2 + 1];
                bf16x8 bh, bl; unpack8(b0, b1, bh, bl);
                f32x4* acc = (nt == 0) ? &acc0 : (nt == 1) ? &acc1 : &acc2;
                *acc = __builtin_amdgcn_mfma_f32_16x16x32_bf16(ah, bh, *acc, 0, 0, 0);
                *acc = __builtin_amdgcn_mfma_f32_16x16x32_bf16(ah, bl, *acc, 0, 0, 0);
                *acc = __builtin_amdgcn_mfma_f32_16x16x32_bf16(al, bh, *acc, 0, 0, 0);
            }
        }
#pragma unroll
        for (int r = 0; r < 4; r++) {
            s_part3[wid][4 * q + r][0 * 16 + c] = acc0[r];
            s_part3[wid][4 * q + r][1 * 16 + c] = acc1[r];
            s_part3[wid][4 * q + r][2 * 16 + c] = acc2[r];
        }
    }
    __syncthreads();

    // ---- reduce K-partials + bias -> offsets (fp32) ----
    for (int idx = tid; idx < P * E1; idx += 256) {
        const int p = idx / E1, e = idx % E1;
        s_off[p][e] = s_part3[0][p][e] + s_part3[1][p][e] +
                      s_part3[2][p][e] + s_part3[3][p][e] + obias[e];
    }
    __syncthreads();

    // ---- ph5: aw2 with deformed kernel points (fp32) + activity masks ----
    {
        unsigned pmask = 0;
#pragma unroll
        for (int k = 0; k < KP; k++) {
            const float kx = s_kp[k][0] + s_off[pg][3 * k + 0];
            const float ky = s_kp[k][1] + s_off[pg][3 * k + 1];
            const float kz = s_kp[k][2] + s_off[pg][3 * k + 2];
            const float dx = nbx - kx, dy = nby - ky, dz = nbz - kz;
            const float av = fmaxf(1.0f - sqrtf(dx * dx + dy * dy + dz * dz), 0.f);
            s_aw[pg][k][mg] = av;
            const unsigned long long b = __ballot(av > 0.f);
            const unsigned any = (tid & 32) ? (unsigned)(b >> 32) : (unsigned)b;
            pmask |= (any ? 1u : 0u) << k;
        }
        if ((tid & 31) == 0) s_act[pg] = pmask;
    }
    __syncthreads();

    const unsigned u2 = s_act[0] | s_act[1] | s_act[2] | s_act[3] |
                        s_act[4] | s_act[5] | s_act[6] | s_act[7];

    // ---- ph6: wf2 (mostly exactly-zero rows -> skipped), packed store ----
    wf_phase(2 * wid + 0, s_act[2 * wid + 0], u2, lane, s_nbr, s_aw, s_wfu, x);
    wf_phase(2 * wid + 1, s_act[2 * wid + 1], u2, lane, s_nbr, s_aw, s_wfu, x);
    __syncthreads();

    // ---- ph7: output via compensated MFMA over active k; wave = e-tile ----
    {
        const int pr = lane & 7;                    // A rows 8..15 duplicate points 0..7
        f32x4 acc = {0.f, 0.f, 0.f, 0.f};
        const uint4* bp = (const uint4*)ww7;
#pragma unroll
        for (int k = 0; k < KP; k++) {
            if (!((u2 >> k) & 1)) continue;
#pragma unroll
            for (int kk = 0; kk < 2; kk++) {
                const int ks = k * 2 + kk;          // contraction chunk, kc = ks*32+q*8+j
                const uint4 a0 = *(const uint4*)&s_wfu[pr][ks * 32 + q * 8];
                const uint4 a1 = *(const uint4*)&s_wfu[pr][ks * 32 + q * 8 + 4];
                bf16x8 ah, al; unpack8(a0, a1, ah, al);
                const uint4 b0 = bp[((ks * 4 + wid) * 64 + lane) * 2 + 0];
                const uint4 b1 = bp[((ks * 4 + wid) * 64 + lane) * 2 + 1];
                bf16x8 bh, bl; unpack8(b0, b1, bh, bl);
                acc = __builtin_amdgcn_mfma_f32_16x16x32_bf16(ah, bh, acc, 0, 0, 0);
                acc = __builtin_amdgcn_mfma_f32_16x16x32_bf16(ah, bl, acc, 0, 0, 0);
                acc = __builtin_amdgcn_mfma_f32_16x16x32_bf16(al, bh, acc, 0, 0, 0);
            }
        }
        // D rows 0..7 = points (rows 8..15 duplicates); direct coalesced store
        if (q < 2) {
#pragma unroll
            for (int r = 0; r < 4; r++)
                out[(base + 4 * q + r) * D + wid * 16 + c] = acc[r];
        }
    }
}

extern "C" void kernel_launch(void* const* d_in, const int* in_sizes, int n_in,
                              void* d_out, int out_size, void* d_ws, size_t ws_size,
                              hipStream_t stream) {
    const float* q   = (const float*)d_in[0];
    const float* s   = (const float*)d_in[1];
    const int*   nb  = (const int*)  d_in[2];
    const float* x   = (const float*)d_in[3];
    const float* kp  = (const float*)d_in[4];
    const float* ow  = (const float*)d_in[5];
    const float* ob  = (const float*)d_in[6];
    const float* w   = (const float*)d_in[7];
    float* out = (float*)d_out;

    unsigned* xw   = (unsigned*)d_ws;                        // 12,800,000 B
    unsigned* oww  = (unsigned*)((char*)d_ws + 12800000);    //    196,608 B
    unsigned* ww7  = (unsigned*)((char*)d_ws + 12996608);    //    245,760 B

    prep_all<<<12932, 256, 0, stream>>>(x, ow, w, xw, oww, ww7);
    kpconv_deform<<<N_PTS / P, 256, 0, stream>>>(q, s, nb, x, kp, ob, xw, oww, ww7, out);
}

// Round 9
// 242.409 us; speedup vs baseline: 3.3723x; 1.0033x over previous
//
#include <hip/hip_runtime.h>

#define N_PTS 50000
#define M 32
#define KP 15
#define D 64
#define E1 45
#define P 8
#define WFS 1048   // wf plane row stride (ushorts): >=1024 enum slots; 1048*2/4=524==12 mod 32

typedef __attribute__((ext_vector_type(8))) short bf16x8;
typedef __attribute__((ext_vector_type(4))) float f32x4;

__device__ __forceinline__ short f2bf(float f) {          // RNE fp32->bf16
    unsigned u = __float_as_uint(f);
    return (short)((u + 0x7fffu + ((u >> 16) & 1u)) >> 16);
}
__device__ __forceinline__ float bf2f(short h) {
    return __uint_as_float(((unsigned)(unsigned short)h) << 16);
}

// ---------------- prep: weights only -> hi/lo bf16 fragment planes ----------
// blocks [0,192):   ow -> owh/owl, frag order [ks32][nt3][lane64][j8], enum i=d*16+k16
// blocks [192,432): w  -> wh/wl,   frag order [ks30][nt4][lane64][j8], enum kc=k*64+d
__global__ void prep_w(const float* __restrict__ ow, const float* __restrict__ w,
                       unsigned short* __restrict__ owh, unsigned short* __restrict__ owl,
                       unsigned short* __restrict__ wh,  unsigned short* __restrict__ wl)
{
    const int b = blockIdx.x, tid = threadIdx.x;
    if (b < 192) {
        const int t = b * 256 + tid;                       // [0, 49152)
        const int j = t & 7, lane = (t >> 3) & 63, rest = t >> 9;
        const int nt = rest % 3, ks = rest / 3;
        const int q = lane >> 4, c = lane & 15;
        const int i = ks * 32 + q * 8 + j, d = i >> 4, k = i & 15, e = nt * 16 + c;
        const float v = (k < KP && e < E1) ? ow[k * (D * E1) + d * E1 + e] : 0.f;
        const short h = f2bf(v);
        owh[t] = (unsigned short)h;
        owl[t] = (unsigned short)f2bf(v - bf2f(h));
    } else {
        const int t = (b - 192) * 256 + tid;               // [0, 61440)
        const int j = t & 7, lane = (t >> 3) & 63, rest = t >> 9;
        const int nt = rest & 3, ks = rest >> 2;           // ks in [0,30)
        const int q = lane >> 4, c = lane & 15;
        const int kc = ks * 32 + q * 8 + j, e = nt * 16 + c;
        const float v = w[kc * D + e];
        const short h = f2bf(v);
        wh[t] = (unsigned short)h;
        wl[t] = (unsigned short)f2bf(v - bf2f(h));
    }
}

// ---------------- sparse fp32 wf (ph6) -> split planes, enum [p][k*64+d] -----
__device__ __forceinline__ void wf_phase(
    int p, unsigned pm, unsigned u, int lane,
    const int (*s_nbr)[M], const float (*s_aw)[KP][M],
    unsigned short (*s_wfh)[WFS], unsigned short (*s_wfl)[WFS],
    const float* __restrict__ x)
{
    float acc[KP];
#pragma unroll
    for (int k = 0; k < KP; k++) acc[k] = 0.f;
    if (pm) {
#pragma unroll
        for (int c = 0; c < M; c += 8) {
            float xv[8];
#pragma unroll
            for (int j = 0; j < 8; j++)
                xv[j] = x[s_nbr[p][c + j] * D + lane];
#pragma unroll
            for (int k = 0; k < KP; k++) {
                if (!((pm >> k) & 1)) continue;
                const float4* a = (const float4*)&s_aw[p][k][c];
                const float4 a0 = a[0], a1 = a[1];
                acc[k] += a0.x * xv[0] + a0.y * xv[1] + a0.z * xv[2] + a0.w * xv[3]
                        + a1.x * xv[4] + a1.y * xv[5] + a1.z * xv[6] + a1.w * xv[7];
            }
        }
    }
#pragma unroll
    for (int k = 0; k < KP; k++) {
        if ((u >> k) & 1) {
            const short h = f2bf(acc[k]);
            s_wfh[p][k * D + lane] = (unsigned short)h;
            s_wfl[p][k * D + lane] = (unsigned short)f2bf(acc[k] - bf2f(h));
        }
    }
}

__global__ __launch_bounds__(256, 3) void kpconv_deform(
    const float* __restrict__ qpts, const float* __restrict__ spts,
    const int*   __restrict__ nbrs, const float* __restrict__ x,
    const float* __restrict__ kpts, const float* __restrict__ obias,
    const unsigned short* __restrict__ owh, const unsigned short* __restrict__ owl,
    const unsigned short* __restrict__ wh,  const unsigned short* __restrict__ wl,
    float* __restrict__ out)
{
    __shared__ int   s_nbr[P][M];
    __shared__ float s_kp[KP][3];
    __shared__ float s_q[P][3];
    __shared__ float s_off[P][E1];
    __shared__ unsigned s_act[P];
    // wf split planes (33536 B): ph2->ph3 enum [p][d*16+k16]; ph6->ph7 [p][k*64+d]
    __shared__ __align__(16) unsigned short s_wfh[P][WFS];
    __shared__ __align__(16) unsigned short s_wfl[P][WFS];
    // bufB (16384 B): aw split planes (ph1->ph2) | ph3 partials | aw fp32 (ph5->ph6)
    __shared__ __align__(16) char s_bufB[16384];
    unsigned short (*s_awh)[512] = (unsigned short(*)[512])s_bufB;          // 8 KB
    unsigned short (*s_awl)[512] = (unsigned short(*)[512])(s_bufB + 8192); // 8 KB
    float (*s_aw)[KP][M]     = (float(*)[KP][M])s_bufB;                     // 15360 B
    float (*s_part3)[16][49] = (float(*)[16][49])s_bufB;                    // 12544 B

    const int tid  = threadIdx.x;
    const int base = blockIdx.x * P;
    const int lane = tid & 63;
    const int wid  = tid >> 6;
    const int q    = lane >> 4, c = lane & 15;
    const int pg   = tid >> 5, mg = tid & 31;   // (p,m) mapping for ph1/ph5

    float nbx, nby, nbz;   // centered neighbor coords, live ph1->ph5

    if (tid < KP * 3) ((float*)s_kp)[tid] = kpts[tid];
    if (tid < P * 3)  ((float*)s_q)[tid]  = qpts[base * 3 + tid];
    __syncthreads();

    // ---- ph1: gather, centered nb, aw1 -> split planes [p][k*32+m] ----
    {
        const int ni = nbrs[(base + pg) * M + mg];
        s_nbr[pg][mg] = ni;
        nbx = spts[ni * 3 + 0] - s_q[pg][0];
        nby = spts[ni * 3 + 1] - s_q[pg][1];
        nbz = spts[ni * 3 + 2] - s_q[pg][2];
#pragma unroll
        for (int k = 0; k < KP; k++) {
            const float dx = nbx - s_kp[k][0];
            const float dy = nby - s_kp[k][1];
            const float dz = nbz - s_kp[k][2];
            const float av = fmaxf(1.0f - sqrtf(dx * dx + dy * dy + dz * dz), 0.f);
            const short h = f2bf(av);
            s_awh[pg][k * 32 + mg] = (unsigned short)h;
            s_awl[pg][k * 32 + mg] = (unsigned short)f2bf(av - bf2f(h));
        }
        s_awh[pg][15 * 32 + mg] = 0;                 // pad row -> exact zeros
        s_awl[pg][15 * 32 + mg] = 0;
    }
    __syncthreads();

    // ---- ph2: wf1 via compensated MFMA: D[k16][d16] = aw[k16][m32]*xg[m32][d16] ----
    {
#pragma unroll
        for (int pi = 0; pi < 2; pi++) {
            const int p = 2 * wid + pi;
            const bf16x8 ah = *(const bf16x8*)&s_awh[p][(lane & 15) * 32 + q * 8];
            const bf16x8 al = *(const bf16x8*)&s_awl[p][(lane & 15) * 32 + q * 8];
            int nbj[8];
#pragma unroll
            for (int j = 0; j < 8; j++) nbj[j] = s_nbr[p][q * 8 + j];
#pragma unroll
            for (int t = 0; t < 4; t++) {
                float xv[8];
#pragma unroll
                for (int j = 0; j < 8; j++)
                    xv[j] = x[nbj[j] * D + t * 16 + c];
                bf16x8 bh, bl;
#pragma unroll
                for (int j = 0; j < 8; j++) {          // in-register split of x
                    const short h = f2bf(xv[j]);
                    bh[j] = h; bl[j] = f2bf(xv[j] - bf2f(h));
                }
                f32x4 dacc = {0.f, 0.f, 0.f, 0.f};
                dacc = __builtin_amdgcn_mfma_f32_16x16x32_bf16(ah, bh, dacc, 0, 0, 0);
                dacc = __builtin_amdgcn_mfma_f32_16x16x32_bf16(ah, bl, dacc, 0, 0, 0);
                dacc = __builtin_amdgcn_mfma_f32_16x16x32_bf16(al, bh, dacc, 0, 0, 0);
                // rows k=4q+r, col d=16t+c -> enum [p][d*16+k], split planes
                short hh[4], ll[4];
#pragma unroll
                for (int r = 0; r < 4; r++) {
                    hh[r] = f2bf(dacc[r]);
                    ll[r] = f2bf(dacc[r] - bf2f(hh[r]));
                }
                union { short s[4]; uint2 v; } uh, ul;
#pragma unroll
                for (int r = 0; r < 4; r++) { uh.s[r] = hh[r]; ul.s[r] = ll[r]; }
                *(uint2*)&s_wfh[p][(t * 16 + c) * 16 + 4 * q] = uh.v;   // max idx 1023
                *(uint2*)&s_wfl[p][(t * 16 + c) * 16 + 4 * q] = ul.v;
            }
        }
    }
    __syncthreads();

    // ---- ph3: offsets via compensated MFMA, contraction split over 4 waves ----
    {
        const int pr = lane & 7;                     // A rows 8..15 duplicate points 0..7
        f32x4 acc0 = {0,0,0,0}, acc1 = {0,0,0,0}, acc2 = {0,0,0,0};
#pragma unroll
        for (int s = 0; s < 8; s++) {
            const int ks = wid * 8 + s;
            const bf16x8 ah = *(const bf16x8*)&s_wfh[pr][ks * 32 + q * 8];
            const bf16x8 al = *(const bf16x8*)&s_wfl[pr][ks * 32 + q * 8];
#pragma unroll
            for (int nt = 0; nt < 3; nt++) {
                const int f = ((ks * 3 + nt) * 64 + lane) * 8;
                const bf16x8 bh = *(const bf16x8*)&owh[f];
                const bf16x8 bl = *(const bf16x8*)&owl[f];
                f32x4* acc = (nt == 0) ? &acc0 : (nt == 1) ? &acc1 : &acc2;
                *acc = __builtin_amdgcn_mfma_f32_16x16x32_bf16(ah, bh, *acc, 0, 0, 0);
                *acc = __builtin_amdgcn_mfma_f32_16x16x32_bf16(ah, bl, *acc, 0, 0, 0);
                *acc = __builtin_amdgcn_mfma_f32_16x16x32_bf16(al, bh, *acc, 0, 0, 0);
            }
        }
#pragma unroll
        for (int r = 0; r < 4; r++) {
            s_part3[wid][4 * q + r][0 * 16 + c] = acc0[r];
            s_part3[wid][4 * q + r][1 * 16 + c] = acc1[r];
            s_part3[wid][4 * q + r][2 * 16 + c] = acc2[r];
        }
    }
    __syncthreads();

    // ---- reduce K-partials + bias -> offsets (fp32) ----
    for (int idx = tid; idx < P * E1; idx += 256) {
        const int p = idx / E1, e = idx % E1;
        s_off[p][e] = s_part3[0][p][e] + s_part3[1][p][e] +
                      s_part3[2][p][e] + s_part3[3][p][e] + obias[e];
    }
    __syncthreads();

    // ---- ph5: aw2 with deformed kernel points (fp32) + activity masks ----
    {
        unsigned pmask = 0;
#pragma unroll
        for (int k = 0; k < KP; k++) {
            const float kx = s_kp[k][0] + s_off[pg][3 * k + 0];
            const float ky = s_kp[k][1] + s_off[pg][3 * k + 1];
            const float kz = s_kp[k][2] + s_off[pg][3 * k + 2];
            const float dx = nbx - kx, dy = nby - ky, dz = nbz - kz;
            const float av = fmaxf(1.0f - sqrtf(dx * dx + dy * dy + dz * dz), 0.f);
            s_aw[pg][k][mg] = av;
            const unsigned long long b = __ballot(av > 0.f);
            const unsigned any = (tid & 32) ? (unsigned)(b >> 32) : (unsigned)b;
            pmask |= (any ? 1u : 0u) << k;
        }
        if ((tid & 31) == 0) s_act[pg] = pmask;
    }
    __syncthreads();

    const unsigned u2 = s_act[0] | s_act[1] | s_act[2] | s_act[3] |
                        s_act[4] | s_act[5] | s_act[6] | s_act[7];

    // ---- ph6: wf2 (mostly exactly-zero rows -> skipped), split-plane store ----
    wf_phase(2 * wid + 0, s_act[2 * wid + 0], u2, lane, s_nbr, s_aw, s_wfh, s_wfl, x);
    wf_phase(2 * wid + 1, s_act[2 * wid + 1], u2, lane, s_nbr, s_aw, s_wfh, s_wfl, x);
    __syncthreads();

    // ---- ph7: output via compensated MFMA over active k; wave = e-tile ----
    {
        const int pr = lane & 7;                    // A rows 8..15 duplicate points 0..7
        f32x4 acc = {0.f, 0.f, 0.f, 0.f};
#pragma unroll
        for (int k = 0; k < KP; k++) {
            if (!((u2 >> k) & 1)) continue;
#pragma unroll
            for (int kk = 0; kk < 2; kk++) {
                const int ks = k * 2 + kk;          // contraction chunk, kc = ks*32+q*8+j
                const bf16x8 ah = *(const bf16x8*)&s_wfh[pr][ks * 32 + q * 8];
                const bf16x8 al = *(const bf16x8*)&s_wfl[pr][ks * 32 + q * 8];
                const int f = ((ks * 4 + wid) * 64 + lane) * 8;
                const bf16x8 bh = *(const bf16x8*)&wh[f];
                const bf16x8 bl = *(const bf16x8*)&wl[f];
                acc = __builtin_amdgcn_mfma_f32_16x16x32_bf16(ah, bh, acc, 0, 0, 0);
                acc = __builtin_amdgcn_mfma_f32_16x16x32_bf16(ah, bl, acc, 0, 0, 0);
                acc = __builtin_amdgcn_mfma_f32_16x16x32_bf16(al, bh, acc, 0, 0, 0);
            }
        }
        // D rows 0..7 = points (rows 8..15 duplicates); direct coalesced store
        if (q < 2) {
#pragma unroll
            for (int r = 0; r < 4; r++)
                out[(base + 4 * q + r) * D + wid * 16 + c] = acc[r];
        }
    }
}

extern "C" void kernel_launch(void* const* d_in, const int* in_sizes, int n_in,
                              void* d_out, int out_size, void* d_ws, size_t ws_size,
                              hipStream_t stream) {
    const float* q   = (const float*)d_in[0];
    const float* s   = (const float*)d_in[1];
    const int*   nb  = (const int*)  d_in[2];
    const float* x   = (const float*)d_in[3];
    const float* kp  = (const float*)d_in[4];
    const float* ow  = (const float*)d_in[5];
    const float* ob  = (const float*)d_in[6];
    const float* w   = (const float*)d_in[7];
    float* out = (float*)d_out;

    unsigned short* owh = (unsigned short*)d_ws;                      //  98,304 B
    unsigned short* owl = (unsigned short*)((char*)d_ws + 98304);     //  98,304 B
    unsigned short* wh  = (unsigned short*)((char*)d_ws + 196608);    // 122,880 B
    unsigned short* wl  = (unsigned short*)((char*)d_ws + 319488);    // 122,880 B

    prep_w<<<432, 256, 0, stream>>>(ow, w, owh, owl, wh, wl);
    kpconv_deform<<<N_PTS / P, 256, 0, stream>>>(q, s, nb, x, kp, ob,
                                                 owh, owl, wh, wl, out);
}

// Round 10
// 229.914 us; speedup vs baseline: 3.5556x; 1.0543x over previous
//
#include <hip/hip_runtime.h>

#define N_PTS 50000
#define M 32
#define KP 15
#define D 64
#define E1 45
#define P 8
#define WFS 1048   // wf plane row stride (ushorts): >=1024 enum slots; 524 dwords == 12 mod 32

typedef __attribute__((ext_vector_type(8))) short bf16x8;
typedef __attribute__((ext_vector_type(4))) float f32x4;

__device__ __forceinline__ short f2bf(float f) {          // RNE fp32->bf16
    unsigned u = __float_as_uint(f);
    return (short)((u + 0x7fffu + ((u >> 16) & 1u)) >> 16);
}
__device__ __forceinline__ float bf2f(short h) {
    return __uint_as_float(((unsigned)(unsigned short)h) << 16);
}

// ---------------- prep: weights only -> hi/lo bf16 fragment planes ----------
// blocks [0,192):   ow -> owh/owl, frag order [ks32][nt3][lane64][j8], enum i=d*16+k16
// blocks [192,432): w  -> wh/wl,   frag order [ks30][nt4][lane64][j8], enum kc=k*64+d
__global__ void prep_w(const float* __restrict__ ow, const float* __restrict__ w,
                       unsigned short* __restrict__ owh, unsigned short* __restrict__ owl,
                       unsigned short* __restrict__ wh,  unsigned short* __restrict__ wl)
{
    const int b = blockIdx.x, tid = threadIdx.x;
    if (b < 192) {
        const int t = b * 256 + tid;                       // [0, 49152)
        const int j = t & 7, lane = (t >> 3) & 63, rest = t >> 9;
        const int nt = rest % 3, ks = rest / 3;
        const int q = lane >> 4, c = lane & 15;
        const int i = ks * 32 + q * 8 + j, d = i >> 4, k = i & 15, e = nt * 16 + c;
        const float v = (k < KP && e < E1) ? ow[k * (D * E1) + d * E1 + e] : 0.f;
        const short h = f2bf(v);
        owh[t] = (unsigned short)h;
        owl[t] = (unsigned short)f2bf(v - bf2f(h));
    } else {
        const int t = (b - 192) * 256 + tid;               // [0, 61440)
        const int j = t & 7, lane = (t >> 3) & 63, rest = t >> 9;
        const int nt = rest & 3, ks = rest >> 2;           // ks in [0,30)
        const int q = lane >> 4, c = lane & 15;
        const int kc = ks * 32 + q * 8 + j, e = nt * 16 + c;
        const float v = w[kc * D + e];
        const short h = f2bf(v);
        wh[t] = (unsigned short)h;
        wl[t] = (unsigned short)f2bf(v - bf2f(h));
    }
}

__global__ __launch_bounds__(256, 3) void kpconv_deform(
    const float* __restrict__ qpts, const float* __restrict__ spts,
    const int*   __restrict__ nbrs, const float* __restrict__ x,
    const float* __restrict__ kpts, const float* __restrict__ obias,
    const unsigned short* __restrict__ owh, const unsigned short* __restrict__ owl,
    const unsigned short* __restrict__ wh,  const unsigned short* __restrict__ wl,
    float* __restrict__ out)
{
    __shared__ int   s_nbr[P][M];
    __shared__ float s_kp[KP][3];
    __shared__ float s_q[P][3];
    __shared__ float s_off[P][E1];
    __shared__ unsigned s_act[P];
    // wf split planes (33536 B): ph2->ph3 enum [p][d*16+k16]; ph6->ph7 [p][k*64+d]
    __shared__ __align__(16) unsigned short s_wfh[P][WFS];
    __shared__ __align__(16) unsigned short s_wfl[P][WFS];
    // bufB (16384 B): aw split planes (ph1->ph2, again ph5->ph6) | ph3 partials
    __shared__ __align__(16) char s_bufB[16384];
    unsigned short (*s_awh)[512] = (unsigned short(*)[512])s_bufB;          // 8 KB
    unsigned short (*s_awl)[512] = (unsigned short(*)[512])(s_bufB + 8192); // 8 KB
    float (*s_part3)[16][49] = (float(*)[16][49])s_bufB;                    // 12544 B

    const int tid  = threadIdx.x;
    const int base = blockIdx.x * P;
    const int lane = tid & 63;
    const int wid  = tid >> 6;
    const int q    = lane >> 4, c = lane & 15;
    const int pg   = tid >> 5, mg = tid & 31;   // (p,m) mapping for ph1/ph5

    float nbx, nby, nbz;        // centered neighbor coords, live ph1->ph5
    bf16x8 fbh[2][4], fbl[2][4]; // cached x B-fragments (ph2 -> ph6), 64 VGPRs

    if (tid < KP * 3) ((float*)s_kp)[tid] = kpts[tid];
    if (tid < P * 3)  ((float*)s_q)[tid]  = qpts[base * 3 + tid];
    __syncthreads();

    // ---- ph1: gather, centered nb, aw1 -> split planes [p][k*32+m] ----
    {
        const int ni = nbrs[(base + pg) * M + mg];
        s_nbr[pg][mg] = ni;
        nbx = spts[ni * 3 + 0] - s_q[pg][0];
        nby = spts[ni * 3 + 1] - s_q[pg][1];
        nbz = spts[ni * 3 + 2] - s_q[pg][2];
#pragma unroll
        for (int k = 0; k < KP; k++) {
            const float dx = nbx - s_kp[k][0];
            const float dy = nby - s_kp[k][1];
            const float dz = nbz - s_kp[k][2];
            const float av = fmaxf(1.0f - sqrtf(dx * dx + dy * dy + dz * dz), 0.f);
            const short h = f2bf(av);
            s_awh[pg][k * 32 + mg] = (unsigned short)h;
            s_awl[pg][k * 32 + mg] = (unsigned short)f2bf(av - bf2f(h));
        }
        s_awh[pg][15 * 32 + mg] = 0;                 // pad row -> exact zeros
        s_awl[pg][15 * 32 + mg] = 0;
    }
    __syncthreads();

    // ---- ph2: wf1 via compensated MFMA; cache x B-fragments in registers ----
    {
#pragma unroll
        for (int pi = 0; pi < 2; pi++) {
            const int p = 2 * wid + pi;
            const bf16x8 ah = *(const bf16x8*)&s_awh[p][(lane & 15) * 32 + q * 8];
            const bf16x8 al = *(const bf16x8*)&s_awl[p][(lane & 15) * 32 + q * 8];
            int nbj[8];
#pragma unroll
            for (int j = 0; j < 8; j++) nbj[j] = s_nbr[p][q * 8 + j];
#pragma unroll
            for (int t = 0; t < 4; t++) {
                float xv[8];
#pragma unroll
                for (int j = 0; j < 8; j++)
                    xv[j] = x[nbj[j] * D + t * 16 + c];
                bf16x8 bh, bl;
#pragma unroll
                for (int j = 0; j < 8; j++) {          // in-register split of x (once)
                    const short h = f2bf(xv[j]);
                    bh[j] = h; bl[j] = f2bf(xv[j] - bf2f(h));
                }
                fbh[pi][t] = bh; fbl[pi][t] = bl;       // cache for ph6
                f32x4 dacc = {0.f, 0.f, 0.f, 0.f};
                dacc = __builtin_amdgcn_mfma_f32_16x16x32_bf16(ah, bh, dacc, 0, 0, 0);
                dacc = __builtin_amdgcn_mfma_f32_16x16x32_bf16(ah, bl, dacc, 0, 0, 0);
                dacc = __builtin_amdgcn_mfma_f32_16x16x32_bf16(al, bh, dacc, 0, 0, 0);
                // rows k=4q+r, col d=16t+c -> enum [p][d*16+k], split planes
                short hh[4], ll[4];
#pragma unroll
                for (int r = 0; r < 4; r++) {
                    hh[r] = f2bf(dacc[r]);
                    ll[r] = f2bf(dacc[r] - bf2f(hh[r]));
                }
                union { short s[4]; uint2 v; } uh, ul;
#pragma unroll
                for (int r = 0; r < 4; r++) { uh.s[r] = hh[r]; ul.s[r] = ll[r]; }
                *(uint2*)&s_wfh[p][(t * 16 + c) * 16 + 4 * q] = uh.v;   // max idx 1023
                *(uint2*)&s_wfl[p][(t * 16 + c) * 16 + 4 * q] = ul.v;
            }
        }
    }
    __syncthreads();

    // ---- ph3: offsets via compensated MFMA, contraction split over 4 waves ----
    {
        const int pr = lane & 7;                     // A rows 8..15 duplicate points 0..7
        f32x4 acc0 = {0,0,0,0}, acc1 = {0,0,0,0}, acc2 = {0,0,0,0};
#pragma unroll
        for (int s = 0; s < 8; s++) {
            const int ks = wid * 8 + s;
            const bf16x8 ah = *(const bf16x8*)&s_wfh[pr][ks * 32 + q * 8];
            const bf16x8 al = *(const bf16x8*)&s_wfl[pr][ks * 32 + q * 8];
#pragma unroll
            for (int nt = 0; nt < 3; nt++) {
                const int f = ((ks * 3 + nt) * 64 + lane) * 8;
                const bf16x8 bh = *(const bf16x8*)&owh[f];
                const bf16x8 bl = *(const bf16x8*)&owl[f];
                f32x4* acc = (nt == 0) ? &acc0 : (nt == 1) ? &acc1 : &acc2;
                *acc = __builtin_amdgcn_mfma_f32_16x16x32_bf16(ah, bh, *acc, 0, 0, 0);
                *acc = __builtin_amdgcn_mfma_f32_16x16x32_bf16(ah, bl, *acc, 0, 0, 0);
                *acc = __builtin_amdgcn_mfma_f32_16x16x32_bf16(al, bh, *acc, 0, 0, 0);
            }
        }
#pragma unroll
        for (int r = 0; r < 4; r++) {
            s_part3[wid][4 * q + r][0 * 16 + c] = acc0[r];
            s_part3[wid][4 * q + r][1 * 16 + c] = acc1[r];
            s_part3[wid][4 * q + r][2 * 16 + c] = acc2[r];
        }
    }
    __syncthreads();

    // ---- reduce K-partials + bias -> offsets (fp32) ----
    for (int idx = tid; idx < P * E1; idx += 256) {
        const int p = idx / E1, e = idx % E1;
        s_off[p][e] = s_part3[0][p][e] + s_part3[1][p][e] +
                      s_part3[2][p][e] + s_part3[3][p][e] + obias[e];
    }
    __syncthreads();

    // ---- ph5: aw2 (deformed kernel points) -> split planes + activity masks ----
    {
        unsigned pmask = 0;
#pragma unroll
        for (int k = 0; k < KP; k++) {
            const float kx = s_kp[k][0] + s_off[pg][3 * k + 0];
            const float ky = s_kp[k][1] + s_off[pg][3 * k + 1];
            const float kz = s_kp[k][2] + s_off[pg][3 * k + 2];
            const float dx = nbx - kx, dy = nby - ky, dz = nbz - kz;
            const float av = fmaxf(1.0f - sqrtf(dx * dx + dy * dy + dz * dz), 0.f);
            const short h = f2bf(av);
            s_awh[pg][k * 32 + mg] = (unsigned short)h;
            s_awl[pg][k * 32 + mg] = (unsigned short)f2bf(av - bf2f(h));
            const unsigned long long b = __ballot(av > 0.f);
            const unsigned any = (tid & 32) ? (unsigned)(b >> 32) : (unsigned)b;
            pmask |= (any ? 1u : 0u) << k;
        }
        s_awh[pg][15 * 32 + mg] = 0;
        s_awl[pg][15 * 32 + mg] = 0;
        if ((tid & 31) == 0) s_act[pg] = pmask;
    }
    __syncthreads();

    const unsigned u2 = s_act[0] | s_act[1] | s_act[2] | s_act[3] |
                        s_act[4] | s_act[5] | s_act[6] | s_act[7];

    // ---- ph6: wf2 via compensated MFMA, reusing cached x fragments ----
    {
#pragma unroll
        for (int pi = 0; pi < 2; pi++) {
            const int p = 2 * wid + pi;
            const bf16x8 ah = *(const bf16x8*)&s_awh[p][(lane & 15) * 32 + q * 8];
            const bf16x8 al = *(const bf16x8*)&s_awl[p][(lane & 15) * 32 + q * 8];
#pragma unroll
            for (int t = 0; t < 4; t++) {
                const bf16x8 bh = fbh[pi][t], bl = fbl[pi][t];
                f32x4 dacc = {0.f, 0.f, 0.f, 0.f};
                dacc = __builtin_amdgcn_mfma_f32_16x16x32_bf16(ah, bh, dacc, 0, 0, 0);
                dacc = __builtin_amdgcn_mfma_f32_16x16x32_bf16(ah, bl, dacc, 0, 0, 0);
                dacc = __builtin_amdgcn_mfma_f32_16x16x32_bf16(al, bh, dacc, 0, 0, 0);
                // rows k=4q+r, col d=16t+c -> enum [p][k*64+d] for ph7
#pragma unroll
                for (int r = 0; r < 4; r++) {
                    const int idx = (4 * q + r) * D + t * 16 + c;
                    const short h = f2bf(dacc[r]);
                    s_wfh[p][idx] = (unsigned short)h;
                    s_wfl[p][idx] = (unsigned short)f2bf(dacc[r] - bf2f(h));
                }
            }
        }
    }
    __syncthreads();

    // ---- ph7: output via compensated MFMA over active k; wave = e-tile ----
    {
        const int pr = lane & 7;                    // A rows 8..15 duplicate points 0..7
        f32x4 acc = {0.f, 0.f, 0.f, 0.f};
#pragma unroll
        for (int k = 0; k < KP; k++) {
            if (!((u2 >> k) & 1)) continue;
#pragma unroll
            for (int kk = 0; kk < 2; kk++) {
                const int ks = k * 2 + kk;          // contraction chunk, kc = ks*32+q*8+j
                const bf16x8 ah = *(const bf16x8*)&s_wfh[pr][ks * 32 + q * 8];
                const bf16x8 al = *(const bf16x8*)&s_wfl[pr][ks * 32 + q * 8];
                const int f = ((ks * 4 + wid) * 64 + lane) * 8;
                const bf16x8 bh = *(const bf16x8*)&wh[f];
                const bf16x8 bl = *(const bf16x8*)&wl[f];
                acc = __builtin_amdgcn_mfma_f32_16x16x32_bf16(ah, bh, acc, 0, 0, 0);
                acc = __builtin_amdgcn_mfma_f32_16x16x32_bf16(ah, bl, acc, 0, 0, 0);
                acc = __builtin_amdgcn_mfma_f32_16x16x32_bf16(al, bh, acc, 0, 0, 0);
            }
        }
        // D rows 0..7 = points (rows 8..15 duplicates); direct coalesced store
        if (q < 2) {
#pragma unroll
            for (int r = 0; r < 4; r++)
                out[(base + 4 * q + r) * D + wid * 16 + c] = acc[r];
        }
    }
}

extern "C" void kernel_launch(void* const* d_in, const int* in_sizes, int n_in,
                              void* d_out, int out_size, void* d_ws, size_t ws_size,
                              hipStream_t stream) {
    const float* q   = (const float*)d_in[0];
    const float* s   = (const float*)d_in[1];
    const int*   nb  = (const int*)  d_in[2];
    const float* x   = (const float*)d_in[3];
    const float* kp  = (const float*)d_in[4];
    const float* ow  = (const float*)d_in[5];
    const float* ob  = (const float*)d_in[6];
    const float* w   = (const float*)d_in[7];
    float* out = (float*)d_out;

    unsigned short* owh = (unsigned short*)d_ws;                      //  98,304 B
    unsigned short* owl = (unsigned short*)((char*)d_ws + 98304);     //  98,304 B
    unsigned short* wh  = (unsigned short*)((char*)d_ws + 196608);    // 122,880 B
    unsigned short* wl  = (unsigned short*)((char*)d_ws + 319488);    // 122,880 B

    prep_w<<<432, 256, 0, stream>>>(ow, w, owh, owl, wh, wl);
    kpconv_deform<<<N_PTS / P, 256, 0, stream>>>(q, s, nb, x, kp, ob,
                                                 owh, owl, wh, wl, out);
}

// Round 11
// 226.001 us; speedup vs baseline: 3.6171x; 1.0173x over previous
//
#include <hip/hip_runtime.h>

#define N_PTS 50000
#define M 32
#define KP 15
#define D 64
#define E1 45
#define P 8
#define WFS 1048   // wf plane row stride (ushorts): >=1024 enum slots; 524 dwords == 12 mod 32

typedef __attribute__((ext_vector_type(8))) short bf16x8;
typedef __attribute__((ext_vector_type(4))) float f32x4;

__device__ __forceinline__ short f2bf(float f) {          // RNE fp32->bf16
    unsigned u = __float_as_uint(f);
    return (short)((u + 0x7fffu + ((u >> 16) & 1u)) >> 16);
}
__device__ __forceinline__ float bf2f(short h) {
    return __uint_as_float(((unsigned)(unsigned short)h) << 16);
}

// packed pair convert: lo16 = bf16(a), hi16 = bf16(b). HW v_cvt_pk_bf16_f32 (RNE)
// when available; bit-exact software fallback otherwise.
#if defined(__HIP_DEVICE_COMPILE__) && __has_builtin(__builtin_amdgcn_cvt_pk_bf16_f32)
typedef __attribute__((ext_vector_type(2))) __bf16 bfp2;
__device__ __forceinline__ unsigned cvtpk(float a, float b) {
    bfp2 r = __builtin_amdgcn_cvt_pk_bf16_f32(a, b);
    union { bfp2 v; unsigned u; } x; x.v = r; return x.u;
}
#else
__device__ __forceinline__ unsigned cvtpk(float a, float b) {
    return (unsigned)(unsigned short)f2bf(a) |
           ((unsigned)(unsigned short)f2bf(b) << 16);
}
#endif

// compensated split of a pair: hu = packed hi(bf16), lu = packed lo(residual bf16)
__device__ __forceinline__ void split2(float a, float b, unsigned& hu, unsigned& lu) {
    hu = cvtpk(a, b);
    const float ra = a - __uint_as_float(hu << 16);
    const float rb = b - __uint_as_float(hu & 0xffff0000u);
    lu = cvtpk(ra, rb);
}

// ---------------- prep: weights only -> hi/lo bf16 fragment planes ----------
// blocks [0,192):   ow -> owh/owl, frag order [ks32][nt3][lane64][j8], enum i=d*16+k16
// blocks [192,432): w  -> wh/wl,   frag order [ks30][nt4][lane64][j8], enum kc=k*64+d
__global__ void prep_w(const float* __restrict__ ow, const float* __restrict__ w,
                       unsigned short* __restrict__ owh, unsigned short* __restrict__ owl,
                       unsigned short* __restrict__ wh,  unsigned short* __restrict__ wl)
{
    const int b = blockIdx.x, tid = threadIdx.x;
    if (b < 192) {
        const int t = b * 256 + tid;                       // [0, 49152)
        const int j = t & 7, lane = (t >> 3) & 63, rest = t >> 9;
        const int nt = rest % 3, ks = rest / 3;
        const int q = lane >> 4, c = lane & 15;
        const int i = ks * 32 + q * 8 + j, d = i >> 4, k = i & 15, e = nt * 16 + c;
        const float v = (k < KP && e < E1) ? ow[k * (D * E1) + d * E1 + e] : 0.f;
        const short h = f2bf(v);
        owh[t] = (unsigned short)h;
        owl[t] = (unsigned short)f2bf(v - bf2f(h));
    } else {
        const int t = (b - 192) * 256 + tid;               // [0, 61440)
        const int j = t & 7, lane = (t >> 3) & 63, rest = t >> 9;
        const int nt = rest & 3, ks = rest >> 2;           // ks in [0,30)
        const int q = lane >> 4, c = lane & 15;
        const int kc = ks * 32 + q * 8 + j, e = nt * 16 + c;
        const float v = w[kc * D + e];
        const short h = f2bf(v);
        wh[t] = (unsigned short)h;
        wl[t] = (unsigned short)f2bf(v - bf2f(h));
    }
}

__global__ __launch_bounds__(256, 3) void kpconv_deform(
    const float* __restrict__ qpts, const float* __restrict__ spts,
    const int*   __restrict__ nbrs, const float* __restrict__ x,
    const float* __restrict__ kpts, const float* __restrict__ obias,
    const unsigned short* __restrict__ owh, const unsigned short* __restrict__ owl,
    const unsigned short* __restrict__ wh,  const unsigned short* __restrict__ wl,
    float* __restrict__ out)
{
    __shared__ int   s_nbr[P][M];
    __shared__ float s_kp[KP][3];
    __shared__ float s_q[P][3];
    __shared__ float s_off[P][E1];
    __shared__ unsigned s_act[P];
    // wf split planes (33536 B): ph2->ph3 enum [p][d*16+k16]; ph6->ph7 [p][k*64+d]
    __shared__ __align__(16) unsigned short s_wfh[P][WFS];
    __shared__ __align__(16) unsigned short s_wfl[P][WFS];
    // bufB (16384 B): aw split planes (ph1->ph2, again ph5->ph6) | ph3 partials
    __shared__ __align__(16) char s_bufB[16384];
    unsigned short (*s_awh)[512] = (unsigned short(*)[512])s_bufB;          // 8 KB
    unsigned short (*s_awl)[512] = (unsigned short(*)[512])(s_bufB + 8192); // 8 KB
    float (*s_part3)[16][49] = (float(*)[16][49])s_bufB;                    // 12544 B

    const int tid  = threadIdx.x;
    const int base = blockIdx.x * P;
    const int lane = tid & 63;
    const int wid  = tid >> 6;
    const int q    = lane >> 4, c = lane & 15;
    const int pg   = tid >> 5, mg = tid & 31;   // (p,m) mapping for ph1/ph5

    float nbx, nby, nbz;        // centered neighbor coords, live ph1->ph5
    bf16x8 fbh[2][4], fbl[2][4]; // cached x B-fragments (ph2 -> ph6)

    if (tid < KP * 3) ((float*)s_kp)[tid] = kpts[tid];
    if (tid < P * 3)  ((float*)s_q)[tid]  = qpts[base * 3 + tid];
    __syncthreads();

    // ---- ph1: gather, centered nb, aw1 -> split planes [p][k*32+m] ----
    {
        const int ni = nbrs[(base + pg) * M + mg];
        s_nbr[pg][mg] = ni;
        nbx = spts[ni * 3 + 0] - s_q[pg][0];
        nby = spts[ni * 3 + 1] - s_q[pg][1];
        nbz = spts[ni * 3 + 2] - s_q[pg][2];
        float av[16];
        av[15] = 0.f;                               // pad row -> exact zeros
#pragma unroll
        for (int k = 0; k < KP; k++) {
            const float dx = nbx - s_kp[k][0];
            const float dy = nby - s_kp[k][1];
            const float dz = nbz - s_kp[k][2];
            av[k] = fmaxf(1.0f - sqrtf(dx * dx + dy * dy + dz * dz), 0.f);
        }
#pragma unroll
        for (int k2 = 0; k2 < 16; k2 += 2) {
            unsigned hu, lu; split2(av[k2], av[k2 + 1], hu, lu);
            s_awh[pg][k2 * 32 + mg]       = (unsigned short)hu;
            s_awh[pg][(k2 + 1) * 32 + mg] = (unsigned short)(hu >> 16);
            s_awl[pg][k2 * 32 + mg]       = (unsigned short)lu;
            s_awl[pg][(k2 + 1) * 32 + mg] = (unsigned short)(lu >> 16);
        }
    }
    __syncthreads();

    // ---- ph2: wf1 via compensated MFMA; cache x B-fragments in registers ----
    {
#pragma unroll
        for (int pi = 0; pi < 2; pi++) {
            const int p = 2 * wid + pi;
            const bf16x8 ah = *(const bf16x8*)&s_awh[p][(lane & 15) * 32 + q * 8];
            const bf16x8 al = *(const bf16x8*)&s_awl[p][(lane & 15) * 32 + q * 8];
            int nbj[8];
#pragma unroll
            for (int j = 0; j < 8; j++) nbj[j] = s_nbr[p][q * 8 + j];
#pragma unroll
            for (int t = 0; t < 4; t++) {
                float xv[8];
#pragma unroll
                for (int j = 0; j < 8; j++)
                    xv[j] = x[nbj[j] * D + t * 16 + c];
                union { bf16x8 v; unsigned u[4]; } bh, bl;
#pragma unroll
                for (int jj = 0; jj < 4; jj++)      // packed in-register split of x
                    split2(xv[2 * jj], xv[2 * jj + 1], bh.u[jj], bl.u[jj]);
                fbh[pi][t] = bh.v; fbl[pi][t] = bl.v;   // cache for ph6
                f32x4 dacc = {0.f, 0.f, 0.f, 0.f};
                dacc = __builtin_amdgcn_mfma_f32_16x16x32_bf16(ah, bh.v, dacc, 0, 0, 0);
                dacc = __builtin_amdgcn_mfma_f32_16x16x32_bf16(ah, bl.v, dacc, 0, 0, 0);
                dacc = __builtin_amdgcn_mfma_f32_16x16x32_bf16(al, bh.v, dacc, 0, 0, 0);
                // rows k=4q+r, col d=16t+c -> enum [p][d*16+k], split planes
                unsigned h01, l01, h23, l23;
                split2(dacc[0], dacc[1], h01, l01);
                split2(dacc[2], dacc[3], h23, l23);
                const uint2 uh = make_uint2(h01, h23);
                const uint2 ul = make_uint2(l01, l23);
                *(uint2*)&s_wfh[p][(t * 16 + c) * 16 + 4 * q] = uh;   // max idx 1023
                *(uint2*)&s_wfl[p][(t * 16 + c) * 16 + 4 * q] = ul;
            }
        }
    }
    __syncthreads();

    // ---- ph3: offsets via compensated MFMA, contraction split over 4 waves ----
    {
        const int pr = lane & 7;                     // A rows 8..15 duplicate points 0..7
        f32x4 acc0 = {0,0,0,0}, acc1 = {0,0,0,0}, acc2 = {0,0,0,0};
#pragma unroll
        for (int s = 0; s < 8; s++) {
            const int ks = wid * 8 + s;
            const bf16x8 ah = *(const bf16x8*)&s_wfh[pr][ks * 32 + q * 8];
            const bf16x8 al = *(const bf16x8*)&s_wfl[pr][ks * 32 + q * 8];
#pragma unroll
            for (int nt = 0; nt < 3; nt++) {
                const int f = ((ks * 3 + nt) * 64 + lane) * 8;
                const bf16x8 bh = *(const bf16x8*)&owh[f];
                const bf16x8 bl = *(const bf16x8*)&owl[f];
                f32x4* acc = (nt == 0) ? &acc0 : (nt == 1) ? &acc1 : &acc2;
                *acc = __builtin_amdgcn_mfma_f32_16x16x32_bf16(ah, bh, *acc, 0, 0, 0);
                *acc = __builtin_amdgcn_mfma_f32_16x16x32_bf16(ah, bl, *acc, 0, 0, 0);
                *acc = __builtin_amdgcn_mfma_f32_16x16x32_bf16(al, bh, *acc, 0, 0, 0);
            }
        }
#pragma unroll
        for (int r = 0; r < 4; r++) {
            s_part3[wid][4 * q + r][0 * 16 + c] = acc0[r];
            s_part3[wid][4 * q + r][1 * 16 + c] = acc1[r];
            s_part3[wid][4 * q + r][2 * 16 + c] = acc2[r];
        }
    }
    __syncthreads();

    // ---- reduce K-partials + bias -> offsets (fp32) ----
    for (int idx = tid; idx < P * E1; idx += 256) {
        const int p = idx / E1, e = idx % E1;
        s_off[p][e] = s_part3[0][p][e] + s_part3[1][p][e] +
                      s_part3[2][p][e] + s_part3[3][p][e] + obias[e];
    }
    __syncthreads();

    // ---- ph5: aw2 (deformed kernel points) -> split planes + activity masks ----
    {
        unsigned pmask = 0;
        float av[16];
        av[15] = 0.f;
#pragma unroll
        for (int k = 0; k < KP; k++) {
            const float kx = s_kp[k][0] + s_off[pg][3 * k + 0];
            const float ky = s_kp[k][1] + s_off[pg][3 * k + 1];
            const float kz = s_kp[k][2] + s_off[pg][3 * k + 2];
            const float dx = nbx - kx, dy = nby - ky, dz = nbz - kz;
            av[k] = fmaxf(1.0f - sqrtf(dx * dx + dy * dy + dz * dz), 0.f);
            const unsigned long long b = __ballot(av[k] > 0.f);
            const unsigned any = (tid & 32) ? (unsigned)(b >> 32) : (unsigned)b;
            pmask |= (any ? 1u : 0u) << k;
        }
#pragma unroll
        for (int k2 = 0; k2 < 16; k2 += 2) {
            unsigned hu, lu; split2(av[k2], av[k2 + 1], hu, lu);
            s_awh[pg][k2 * 32 + mg]       = (unsigned short)hu;
            s_awh[pg][(k2 + 1) * 32 + mg] = (unsigned short)(hu >> 16);
            s_awl[pg][k2 * 32 + mg]       = (unsigned short)lu;
            s_awl[pg][(k2 + 1) * 32 + mg] = (unsigned short)(lu >> 16);
        }
        if ((tid & 31) == 0) s_act[pg] = pmask;
    }
    __syncthreads();

    const unsigned u2 = s_act[0] | s_act[1] | s_act[2] | s_act[3] |
                        s_act[4] | s_act[5] | s_act[6] | s_act[7];

    // ---- ph6: wf2 via compensated MFMA, reusing cached x fragments ----
    {
        const unsigned m4 = (u2 >> (4 * q)) & 15u;   // active mask for this quad's rows
#pragma unroll
        for (int pi = 0; pi < 2; pi++) {
            const int p = 2 * wid + pi;
            const bf16x8 ah = *(const bf16x8*)&s_awh[p][(lane & 15) * 32 + q * 8];
            const bf16x8 al = *(const bf16x8*)&s_awl[p][(lane & 15) * 32 + q * 8];
#pragma unroll
            for (int t = 0; t < 4; t++) {
                const bf16x8 bh = fbh[pi][t], bl = fbl[pi][t];
                f32x4 dacc = {0.f, 0.f, 0.f, 0.f};
                dacc = __builtin_amdgcn_mfma_f32_16x16x32_bf16(ah, bh, dacc, 0, 0, 0);
                dacc = __builtin_amdgcn_mfma_f32_16x16x32_bf16(ah, bl, dacc, 0, 0, 0);
                dacc = __builtin_amdgcn_mfma_f32_16x16x32_bf16(al, bh, dacc, 0, 0, 0);
                // rows k=4q+r, col d=16t+c -> enum [p][k*64+d]; only active rows
                unsigned h01, l01, h23, l23;
                split2(dacc[0], dacc[1], h01, l01);
                split2(dacc[2], dacc[3], h23, l23);
                const int col = t * 16 + c, kb = 4 * q;
                if (m4 & 1) { s_wfh[p][(kb + 0) * D + col] = (unsigned short)h01;
                              s_wfl[p][(kb + 0) * D + col] = (unsigned short)l01; }
                if (m4 & 2) { s_wfh[p][(kb + 1) * D + col] = (unsigned short)(h01 >> 16);
                              s_wfl[p][(kb + 1) * D + col] = (unsigned short)(l01 >> 16); }
                if (m4 & 4) { s_wfh[p][(kb + 2) * D + col] = (unsigned short)h23;
                              s_wfl[p][(kb + 2) * D + col] = (unsigned short)l23; }
                if (m4 & 8) { s_wfh[p][(kb + 3) * D + col] = (unsigned short)(h23 >> 16);
                              s_wfl[p][(kb + 3) * D + col] = (unsigned short)(l23 >> 16); }
            }
        }
    }
    __syncthreads();

    // ---- ph7: output via compensated MFMA over active k; wave = e-tile ----
    {
        const int pr = lane & 7;                    // A rows 8..15 duplicate points 0..7
        f32x4 acc = {0.f, 0.f, 0.f, 0.f};
#pragma unroll
        for (int k = 0; k < KP; k++) {
            if (!((u2 >> k) & 1)) continue;
#pragma unroll
            for (int kk = 0; kk < 2; kk++) {
                const int ks = k * 2 + kk;          // contraction chunk, kc = ks*32+q*8+j
                const bf16x8 ah = *(const bf16x8*)&s_wfh[pr][ks * 32 + q * 8];
                const bf16x8 al = *(const bf16x8*)&s_wfl[pr][ks * 32 + q * 8];
                const int f = ((ks * 4 + wid) * 64 + lane) * 8;
                const bf16x8 bh = *(const bf16x8*)&wh[f];
                const bf16x8 bl = *(const bf16x8*)&wl[f];
                acc = __builtin_amdgcn_mfma_f32_16x16x32_bf16(ah, bh, acc, 0, 0, 0);
                acc = __builtin_amdgcn_mfma_f32_16x16x32_bf16(ah, bl, acc, 0, 0, 0);
                acc = __builtin_amdgcn_mfma_f32_16x16x32_bf16(al, bh, acc, 0, 0, 0);
            }
        }
        // D rows 0..7 = points (rows 8..15 duplicates); direct coalesced store
        if (q < 2) {
#pragma unroll
            for (int r = 0; r < 4; r++)
                out[(base + 4 * q + r) * D + wid * 16 + c] = acc[r];
        }
    }
}

extern "C" void kernel_launch(void* const* d_in, const int* in_sizes, int n_in,
                              void* d_out, int out_size, void* d_ws, size_t ws_size,
                              hipStream_t stream) {
    const float* q   = (const float*)d_in[0];
    const float* s   = (const float*)d_in[1];
    const int*   nb  = (const int*)  d_in[2];
    const float* x   = (const float*)d_in[3];
    const float* kp  = (const float*)d_in[4];
    const float* ow  = (const float*)d_in[5];
    const float* ob  = (const float*)d_in[6];
    const float* w   = (const float*)d_in[7];
    float* out = (float*)d_out;

    unsigned short* owh = (unsigned short*)d_ws;                      //  98,304 B
    unsigned short* owl = (unsigned short*)((char*)d_ws + 98304);     //  98,304 B
    unsigned short* wh  = (unsigned short*)((char*)d_ws + 196608);    // 122,880 B
    unsigned short* wl  = (unsigned short*)((char*)d_ws + 319488);    // 122,880 B

    prep_w<<<432, 256, 0, stream>>>(ow, w, owh, owl, wh, wl);
    kpconv_deform<<<N_PTS / P, 256, 0, stream>>>(q, s, nb, x, kp, ob,
                                                 owh, owl, wh, wl, out);
}

// Round 12
// 222.742 us; speedup vs baseline: 3.6701x; 1.0146x over previous
//
#include <hip/hip_runtime.h>

#define N_PTS 50000
#define M 32
#define KP 15
#define D 64
#define E1 45
#define P 8
#define WFS 1048   // wf plane row stride (ushorts): >=1024 enum slots

typedef __attribute__((ext_vector_type(8))) short bf16x8;
typedef __attribute__((ext_vector_type(4))) float f32x4;

__device__ __forceinline__ short f2bf(float f) {          // RNE fp32->bf16
    unsigned u = __float_as_uint(f);
    return (short)((u + 0x7fffu + ((u >> 16) & 1u)) >> 16);
}
__device__ __forceinline__ float bf2f(short h) {
    return __uint_as_float(((unsigned)(unsigned short)h) << 16);
}

#if defined(__HIP_DEVICE_COMPILE__) && __has_builtin(__builtin_amdgcn_cvt_pk_bf16_f32)
typedef __attribute__((ext_vector_type(2))) __bf16 bfp2;
__device__ __forceinline__ unsigned cvtpk(float a, float b) {
    bfp2 r = __builtin_amdgcn_cvt_pk_bf16_f32(a, b);
    union { bfp2 v; unsigned u; } x; x.v = r; return x.u;
}
#else
__device__ __forceinline__ unsigned cvtpk(float a, float b) {
    return (unsigned)(unsigned short)f2bf(a) |
           ((unsigned)(unsigned short)f2bf(b) << 16);
}
#endif

// compensated split of a pair: hu = packed hi(bf16), lu = packed residual(bf16)
__device__ __forceinline__ void split2(float a, float b, unsigned& hu, unsigned& lu) {
    hu = cvtpk(a, b);
    const float ra = a - __uint_as_float(hu << 16);
    const float rb = b - __uint_as_float(hu & 0xffff0000u);
    lu = cvtpk(ra, rb);
}
// packed single value: lo16 = hi term, hi16 = residual
__device__ __forceinline__ unsigned splitpack(float v) {
    const short h = f2bf(v);
    const short l = f2bf(v - bf2f(h));
    return (unsigned)(unsigned short)h | ((unsigned)(unsigned short)l << 16);
}

#if defined(__HIP_DEVICE_COMPILE__) && __has_builtin(__builtin_amdgcn_perm)
__device__ __forceinline__ unsigned permb(unsigned a, unsigned b, unsigned sel) {
    return __builtin_amdgcn_perm(a, b, sel);
}
#else
__device__ __forceinline__ unsigned permb(unsigned a, unsigned b, unsigned sel) {
    if (sel == 0x05040100u) return (b & 0xffffu) | (a << 16);
    return (b >> 16) | (a & 0xffff0000u);
}
#endif

// ---------------- fused prep (one launch; writes d_ws) -----------------------
// blocks [0,12500): x -> packed split-bf16 dwords
// blocks [12500,12692): ow -> owh/owl planes; contraction pos swizzled:
//     orig = pos ^ (((pos>>6)&3)<<2); d = orig>>4, k = orig&15 (zero pad k==15/e>=45)
// blocks [12692,12932): w -> wh/wl planes; pos = k*64+dsw, d = dsw ^ ((k>>2)<<4)
__global__ void prep_all(const float* __restrict__ x, const float* __restrict__ ow,
                         const float* __restrict__ w, unsigned* __restrict__ xw,
                         unsigned short* __restrict__ owh, unsigned short* __restrict__ owl,
                         unsigned short* __restrict__ wh,  unsigned short* __restrict__ wl)
{
    const int b = blockIdx.x, tid = threadIdx.x;
    if (b < 12500) {
        const int i = b * 256 + tid;
        xw[i] = splitpack(x[i]);
    } else if (b < 12692) {
        const int t = (b - 12500) * 256 + tid;              // [0, 49152)
        const int j = t & 7, lane = (t >> 3) & 63, rest = t >> 9;
        const int nt = rest % 3, ks = rest / 3;
        const int q = lane >> 4, c = lane & 15;
        const int pos  = ks * 32 + q * 8 + j;
        const int orig = pos ^ (((pos >> 6) & 3) << 2);
        const int d = orig >> 4, k = orig & 15, e = nt * 16 + c;
        const float v = (k < KP && e < E1) ? ow[k * (D * E1) + d * E1 + e] : 0.f;
        const short h = f2bf(v);
        owh[t] = (unsigned short)h;
        owl[t] = (unsigned short)f2bf(v - bf2f(h));
    } else {
        const int t = (b - 12692) * 256 + tid;              // [0, 61440)
        const int j = t & 7, lane = (t >> 3) & 63, rest = t >> 9;
        const int nt = rest & 3, ks = rest >> 2;            // ks in [0,30)
        const int q = lane >> 4, c = lane & 15;
        const int pos = ks * 32 + q * 8 + j;                // [0,960)
        const int k = pos >> 6, dsw = pos & 63;
        const int d = dsw ^ (((k >> 2) & 3) << 4);
        const int e = nt * 16 + c;
        const float v = w[k * (D * D) + d * D + e];
        const short h = f2bf(v);
        wh[t] = (unsigned short)h;
        wl[t] = (unsigned short)f2bf(v - bf2f(h));
    }
}

__global__ __launch_bounds__(256, 3) void kpconv_deform(
    const float* __restrict__ qpts, const float* __restrict__ spts,
    const int*   __restrict__ nbrs, const float* __restrict__ kpts,
    const float* __restrict__ obias,
    const unsigned* __restrict__ xw,
    const unsigned short* __restrict__ owh, const unsigned short* __restrict__ owl,
    const unsigned short* __restrict__ wh,  const unsigned short* __restrict__ wl,
    float* __restrict__ out)
{
    __shared__ int   s_nbr[P][M];
    __shared__ float s_kp[KP][3];
    __shared__ float s_q[P][3];
    __shared__ float s_off[P][E1];
    __shared__ unsigned s_act[4];
    // wf split planes: ph2->ph3 swizzled enum (1024); ph6->ph7 swizzled enum (960)
    __shared__ __align__(16) unsigned short s_wfh[P][WFS];
    __shared__ __align__(16) unsigned short s_wfl[P][WFS];
    // bufB: aw split planes (ph1->ph2, ph5->ph6) | ph3 partials
    __shared__ __align__(16) char s_bufB[16384];
    unsigned short (*s_awh)[512] = (unsigned short(*)[512])s_bufB;          // 8 KB
    unsigned short (*s_awl)[512] = (unsigned short(*)[512])(s_bufB + 8192); // 8 KB
    float (*s_part3)[16][49] = (float(*)[16][49])s_bufB;                    // 12544 B

    const int tid  = threadIdx.x;
    const int base = blockIdx.x * P;
    const int lane = tid & 63;
    const int wid  = tid >> 6;
    const int q    = lane >> 4, c = lane & 15;
    const int pg   = tid >> 5, mg = tid & 31;   // (p,m) mapping for ph1/ph5

    float nbx, nby, nbz;        // centered neighbor coords, live ph1->ph5
    bf16x8 fbh[2][4], fbl[2][4]; // cached x B-fragments (ph2 -> ph6)

    if (tid < KP * 3) ((float*)s_kp)[tid] = kpts[tid];
    if (tid < P * 3)  ((float*)s_q)[tid]  = qpts[base * 3 + tid];
    __syncthreads();

    // ---- ph1: gather, centered nb, aw1 -> split planes [p][k*32+m] ----
    {
        const int ni = nbrs[(base + pg) * M + mg];
        s_nbr[pg][mg] = ni;
        nbx = spts[ni * 3 + 0] - s_q[pg][0];
        nby = spts[ni * 3 + 1] - s_q[pg][1];
        nbz = spts[ni * 3 + 2] - s_q[pg][2];
        float av[16];
        av[15] = 0.f;                               // pad row -> exact zeros
#pragma unroll
        for (int k = 0; k < KP; k++) {
            const float dx = nbx - s_kp[k][0];
            const float dy = nby - s_kp[k][1];
            const float dz = nbz - s_kp[k][2];
            av[k] = fmaxf(1.0f - sqrtf(dx * dx + dy * dy + dz * dz), 0.f);
        }
#pragma unroll
        for (int k2 = 0; k2 < 16; k2 += 2) {
            unsigned hu, lu; split2(av[k2], av[k2 + 1], hu, lu);
            s_awh[pg][k2 * 32 + mg]       = (unsigned short)hu;
            s_awh[pg][(k2 + 1) * 32 + mg] = (unsigned short)(hu >> 16);
            s_awl[pg][k2 * 32 + mg]       = (unsigned short)lu;
            s_awl[pg][(k2 + 1) * 32 + mg] = (unsigned short)(lu >> 16);
        }
    }
    __syncthreads();

    // ---- ph2: wf1 via compensated MFMA; cache x fragments; swizzled store ----
    {
        const int hc = c >> 2;
#pragma unroll
        for (int pi = 0; pi < 2; pi++) {
            const int p = 2 * wid + pi;
            const bf16x8 ah = *(const bf16x8*)&s_awh[p][(lane & 15) * 32 + q * 8];
            const bf16x8 al = *(const bf16x8*)&s_awl[p][(lane & 15) * 32 + q * 8];
            int nbj[8];
#pragma unroll
            for (int j = 0; j < 8; j++) nbj[j] = s_nbr[p][q * 8 + j];
#pragma unroll
            for (int t = 0; t < 4; t++) {
                unsigned g[8];
#pragma unroll
                for (int j = 0; j < 8; j++)
                    g[j] = xw[nbj[j] * D + t * 16 + c];
                union { bf16x8 v; unsigned u[4]; } bh, bl;
#pragma unroll
                for (int jj = 0; jj < 4; jj++) {    // perm-unpack hi/lo planes
                    bh.u[jj] = permb(g[2 * jj + 1], g[2 * jj], 0x05040100u);
                    bl.u[jj] = permb(g[2 * jj + 1], g[2 * jj], 0x07060302u);
                }
                fbh[pi][t] = bh.v; fbl[pi][t] = bl.v;   // cache for ph6
                f32x4 dacc = {0.f, 0.f, 0.f, 0.f};
                dacc = __builtin_amdgcn_mfma_f32_16x16x32_bf16(ah, bh.v, dacc, 0, 0, 0);
                dacc = __builtin_amdgcn_mfma_f32_16x16x32_bf16(ah, bl.v, dacc, 0, 0, 0);
                dacc = __builtin_amdgcn_mfma_f32_16x16x32_bf16(al, bh.v, dacc, 0, 0, 0);
                unsigned h01, l01, h23, l23;
                split2(dacc[0], dacc[1], h01, l01);
                split2(dacc[2], dacc[3], h23, l23);
                // swizzled enum: pos = (t*16+c)*16 + 4*(q^hc) (+r)
                const int eb = (t * 16 + c) * 16 + 4 * (q ^ hc);
                *(uint2*)&s_wfh[p][eb] = make_uint2(h01, h23);
                *(uint2*)&s_wfl[p][eb] = make_uint2(l01, l23);
            }
        }
    }
    __syncthreads();

    // ---- ph3: offsets via compensated MFMA, contraction split over 4 waves ----
    {
        const int pr = lane & 7;                     // A rows 8..15 duplicate points 0..7
        f32x4 acc0 = {0,0,0,0}, acc1 = {0,0,0,0}, acc2 = {0,0,0,0};
#pragma unroll
        for (int s = 0; s < 8; s++) {
            const int ks = wid * 8 + s;
            const bf16x8 ah = *(const bf16x8*)&s_wfh[pr][ks * 32 + q * 8];
            const bf16x8 al = *(const bf16x8*)&s_wfl[pr][ks * 32 + q * 8];
#pragma unroll
            for (int nt = 0; nt < 3; nt++) {
                const int f = ((ks * 3 + nt) * 64 + lane) * 8;
                const bf16x8 bh = *(const bf16x8*)&owh[f];
                const bf16x8 bl = *(const bf16x8*)&owl[f];
                f32x4* acc = (nt == 0) ? &acc0 : (nt == 1) ? &acc1 : &acc2;
                *acc = __builtin_amdgcn_mfma_f32_16x16x32_bf16(ah, bh, *acc, 0, 0, 0);
                *acc = __builtin_amdgcn_mfma_f32_16x16x32_bf16(ah, bl, *acc, 0, 0, 0);
                *acc = __builtin_amdgcn_mfma_f32_16x16x32_bf16(al, bh, *acc, 0, 0, 0);
            }
        }
#pragma unroll
        for (int r = 0; r < 4; r++) {
            s_part3[wid][4 * q + r][0 * 16 + c] = acc0[r];
            s_part3[wid][4 * q + r][1 * 16 + c] = acc1[r];
            s_part3[wid][4 * q + r][2 * 16 + c] = acc2[r];
        }
    }
    __syncthreads();

    // ---- reduce K-partials + bias -> offsets (fp32) ----
    for (int idx = tid; idx < P * E1; idx += 256) {
        const int p = idx / E1, e = idx % E1;
        s_off[p][e] = s_part3[0][p][e] + s_part3[1][p][e] +
                      s_part3[2][p][e] + s_part3[3][p][e] + obias[e];
    }
    __syncthreads();

    // ---- ph5: aw2 (deformed kernel points) -> split planes + joint wave mask ----
    {
        unsigned pmask = 0;
        float av[16];
        av[15] = 0.f;
#pragma unroll
        for (int k = 0; k < KP; k++) {
            const float kx = s_kp[k][0] + s_off[pg][3 * k + 0];
            const float ky = s_kp[k][1] + s_off[pg][3 * k + 1];
            const float kz = s_kp[k][2] + s_off[pg][3 * k + 2];
            const float dx = nbx - kx, dy = nby - ky, dz = nbz - kz;
            av[k] = fmaxf(1.0f - sqrtf(dx * dx + dy * dy + dz * dz), 0.f);
            pmask |= (__ballot(av[k] > 0.f) ? 1u : 0u) << k;   // union of wave's 2 pts
        }
#pragma unroll
        for (int k2 = 0; k2 < 16; k2 += 2) {
            unsigned hu, lu; split2(av[k2], av[k2 + 1], hu, lu);
            s_awh[pg][k2 * 32 + mg]       = (unsigned short)hu;
            s_awh[pg][(k2 + 1) * 32 + mg] = (unsigned short)(hu >> 16);
            s_awl[pg][k2 * 32 + mg]       = (unsigned short)lu;
            s_awl[pg][(k2 + 1) * 32 + mg] = (unsigned short)(lu >> 16);
        }
        if (lane == 0) s_act[wid] = pmask;
    }
    __syncthreads();

    const unsigned u2 = s_act[0] | s_act[1] | s_act[2] | s_act[3];

    // ---- ph6: wf2 via compensated MFMA; swizzled conflict-free stores ----
    {
#pragma unroll
        for (int pi = 0; pi < 2; pi++) {
            const int p = 2 * wid + pi;
            const bf16x8 ah = *(const bf16x8*)&s_awh[p][(lane & 15) * 32 + q * 8];
            const bf16x8 al = *(const bf16x8*)&s_awl[p][(lane & 15) * 32 + q * 8];
#pragma unroll
            for (int t = 0; t < 4; t++) {
                const bf16x8 bh = fbh[pi][t], bl = fbl[pi][t];
                f32x4 dacc = {0.f, 0.f, 0.f, 0.f};
                dacc = __builtin_amdgcn_mfma_f32_16x16x32_bf16(ah, bh, dacc, 0, 0, 0);
                dacc = __builtin_amdgcn_mfma_f32_16x16x32_bf16(ah, bl, dacc, 0, 0, 0);
                dacc = __builtin_amdgcn_mfma_f32_16x16x32_bf16(al, bh, dacc, 0, 0, 0);
                unsigned h01, l01, h23, l23;
                split2(dacc[0], dacc[1], h01, l01);
                split2(dacc[2], dacc[3], h23, l23);
                // swizzled enum: pos = k*64 + ((t^q)*16 + c), k = 4q+r (k>>2 == q)
                const int col = ((t ^ q) * 16 + c), kb = 4 * q;
                s_wfh[p][(kb + 0) * 64 + col] = (unsigned short)h01;
                s_wfl[p][(kb + 0) * 64 + col] = (unsigned short)l01;
                s_wfh[p][(kb + 1) * 64 + col] = (unsigned short)(h01 >> 16);
                s_wfl[p][(kb + 1) * 64 + col] = (unsigned short)(l01 >> 16);
                s_wfh[p][(kb + 2) * 64 + col] = (unsigned short)h23;
                s_wfl[p][(kb + 2) * 64 + col] = (unsigned short)l23;
                s_wfh[p][(kb + 3) * 64 + col] = (unsigned short)(h23 >> 16);
                s_wfl[p][(kb + 3) * 64 + col] = (unsigned short)(l23 >> 16);
            }
        }
    }
    __syncthreads();

    // ---- ph7: output via compensated MFMA over active k; wave = e-tile ----
    {
        const int pr = lane & 7;                    // A rows 8..15 duplicate points 0..7
        f32x4 acc = {0.f, 0.f, 0.f, 0.f};
#pragma unroll
        for (int k = 0; k < KP; k++) {
            if (!((u2 >> k) & 1)) continue;
#pragma unroll
            for (int kk = 0; kk < 2; kk++) {
                const int ks = k * 2 + kk;
                const bf16x8 ah = *(const bf16x8*)&s_wfh[pr][ks * 32 + q * 8];
                const bf16x8 al = *(const bf16x8*)&s_wfl[pr][ks * 32 + q * 8];
                const int f = ((ks * 4 + wid) * 64 + lane) * 8;
                const bf16x8 bh = *(const bf16x8*)&wh[f];
                const bf16x8 bl = *(const bf16x8*)&wl[f];
                acc = __builtin_amdgcn_mfma_f32_16x16x32_bf16(ah, bh, acc, 0, 0, 0);
                acc = __builtin_amdgcn_mfma_f32_16x16x32_bf16(ah, bl, acc, 0, 0, 0);
                acc = __builtin_amdgcn_mfma_f32_16x16x32_bf16(al, bh, acc, 0, 0, 0);
            }
        }
        // D rows 0..7 = points (rows 8..15 duplicates); direct coalesced store
        if (q < 2) {
#pragma unroll
            for (int r = 0; r < 4; r++)
                out[(base + 4 * q + r) * D + wid * 16 + c] = acc[r];
        }
    }
}

extern "C" void kernel_launch(void* const* d_in, const int* in_sizes, int n_in,
                              void* d_out, int out_size, void* d_ws, size_t ws_size,
                              hipStream_t stream) {
    const float* q   = (const float*)d_in[0];
    const float* s   = (const float*)d_in[1];
    const int*   nb  = (const int*)  d_in[2];
    const float* x   = (const float*)d_in[3];
    const float* kp  = (const float*)d_in[4];
    const float* ow  = (const float*)d_in[5];
    const float* ob  = (const float*)d_in[6];
    const float* w   = (const float*)d_in[7];
    float* out = (float*)d_out;

    unsigned*       xw  = (unsigned*)d_ws;                            // 12,800,000 B
    unsigned short* owh = (unsigned short*)((char*)d_ws + 12800000);  //     98,304 B
    unsigned short* owl = (unsigned short*)((char*)d_ws + 12898304);  //     98,304 B
    unsigned short* wh  = (unsigned short*)((char*)d_ws + 12996608);  //    122,880 B
    unsigned short* wl  = (unsigned short*)((char*)d_ws + 13119488);  //    122,880 B

    prep_all<<<12932, 256, 0, stream>>>(x, ow, w, xw, owh, owl, wh, wl);
    kpconv_deform<<<N_PTS / P, 256, 0, stream>>>(q, s, nb, kp, ob,
                                                 xw, owh, owl, wh, wl, out);
}

// Round 13
// 219.792 us; speedup vs baseline: 3.7193x; 1.0134x over previous
//
#include <hip/hip_runtime.h>

#define N_PTS 50000
#define M 32
#define KP 15
#define D 64
#define E1 45
#define P 8
#define WFS 1048   // wf plane row stride (ushorts): >=1024 enum slots

typedef __attribute__((ext_vector_type(8))) short bf16x8;
typedef __attribute__((ext_vector_type(4))) float f32x4;

__device__ __forceinline__ short f2bf(float f) {          // RNE fp32->bf16
    unsigned u = __float_as_uint(f);
    return (short)((u + 0x7fffu + ((u >> 16) & 1u)) >> 16);
}
__device__ __forceinline__ float bf2f(short h) {
    return __uint_as_float(((unsigned)(unsigned short)h) << 16);
}

#if defined(__HIP_DEVICE_COMPILE__) && __has_builtin(__builtin_amdgcn_cvt_pk_bf16_f32)
typedef __attribute__((ext_vector_type(2))) __bf16 bfp2;
__device__ __forceinline__ unsigned cvtpk(float a, float b) {
    bfp2 r = __builtin_amdgcn_cvt_pk_bf16_f32(a, b);
    union { bfp2 v; unsigned u; } x; x.v = r; return x.u;
}
#else
__device__ __forceinline__ unsigned cvtpk(float a, float b) {
    return (unsigned)(unsigned short)f2bf(a) |
           ((unsigned)(unsigned short)f2bf(b) << 16);
}
#endif

// compensated split of a pair: hu = packed hi(bf16), lu = packed residual(bf16)
__device__ __forceinline__ void split2(float a, float b, unsigned& hu, unsigned& lu) {
    hu = cvtpk(a, b);
    const float ra = a - __uint_as_float(hu << 16);
    const float rb = b - __uint_as_float(hu & 0xffff0000u);
    lu = cvtpk(ra, rb);
}
// packed single value: lo16 = hi term, hi16 = residual
__device__ __forceinline__ unsigned splitpack(float v) {
    const short h = f2bf(v);
    const short l = f2bf(v - bf2f(h));
    return (unsigned)(unsigned short)h | ((unsigned)(unsigned short)l << 16);
}

#if defined(__HIP_DEVICE_COMPILE__) && __has_builtin(__builtin_amdgcn_perm)
__device__ __forceinline__ unsigned permb(unsigned a, unsigned b, unsigned sel) {
    return __builtin_amdgcn_perm(a, b, sel);
}
#else
__device__ __forceinline__ unsigned permb(unsigned a, unsigned b, unsigned sel) {
    if (sel == 0x05040100u) return (b & 0xffffu) | (a << 16);
    return (b >> 16) | (a & 0xffff0000u);
}
#endif

// ---------------- fused prep (one launch; writes d_ws) -----------------------
// blocks [0,12500): x -> packed split-bf16 dwords
// blocks [12500,12692): ow -> owh/owl planes; pos swizzle:
//     orig = pos ^ (((pos>>6)&3)<<2); d = orig>>4, k = orig&15 (zero pad k==15/e>=45)
// blocks [12692,12932): w -> wh/wl planes; enum pos = k*64 + dsw, d = dsw ^ ((k&7)<<3)
__global__ void prep_all(const float* __restrict__ x, const float* __restrict__ ow,
                         const float* __restrict__ w, unsigned* __restrict__ xw,
                         unsigned short* __restrict__ owh, unsigned short* __restrict__ owl,
                         unsigned short* __restrict__ wh,  unsigned short* __restrict__ wl)
{
    const int b = blockIdx.x, tid = threadIdx.x;
    if (b < 12500) {
        const int i = b * 256 + tid;
        xw[i] = splitpack(x[i]);
    } else if (b < 12692) {
        const int t = (b - 12500) * 256 + tid;              // [0, 49152)
        const int j = t & 7, lane = (t >> 3) & 63, rest = t >> 9;
        const int nt = rest % 3, ks = rest / 3;
        const int q = lane >> 4, c = lane & 15;
        const int pos  = ks * 32 + q * 8 + j;
        const int orig = pos ^ (((pos >> 6) & 3) << 2);
        const int d = orig >> 4, k = orig & 15, e = nt * 16 + c;
        const float v = (k < KP && e < E1) ? ow[k * (D * E1) + d * E1 + e] : 0.f;
        const short h = f2bf(v);
        owh[t] = (unsigned short)h;
        owl[t] = (unsigned short)f2bf(v - bf2f(h));
    } else {
        const int t = (b - 12692) * 256 + tid;              // [0, 61440)
        const int j = t & 7, lane = (t >> 3) & 63, rest = t >> 9;
        const int nt = rest & 3, ks = rest >> 2;            // ks in [0,30)
        const int q = lane >> 4, c = lane & 15;
        const int pos = ks * 32 + q * 8 + j;                // [0,960)
        const int k = pos >> 6, dsw = pos & 63;
        const int d = dsw ^ ((k & 7) << 3);
        const int e = nt * 16 + c;
        const float v = w[k * (D * D) + d * D + e];
        const short h = f2bf(v);
        wh[t] = (unsigned short)h;
        wl[t] = (unsigned short)f2bf(v - bf2f(h));
    }
}

__global__ __launch_bounds__(256, 3) void kpconv_deform(
    const float* __restrict__ qpts, const float* __restrict__ spts,
    const int*   __restrict__ nbrs, const float* __restrict__ kpts,
    const float* __restrict__ obias,
    const unsigned* __restrict__ xw,
    const unsigned short* __restrict__ owh, const unsigned short* __restrict__ owl,
    const unsigned short* __restrict__ wh,  const unsigned short* __restrict__ wl,
    float* __restrict__ out)
{
    __shared__ int   s_nbr[P][M];
    __shared__ float s_kp[KP][3];
    __shared__ float s_q[P][3];
    __shared__ float s_off[P][E1];
    __shared__ unsigned s_act[4];
    // wf split planes: ph2->ph3 enum (1024 slots); ph6->ph7 enum k*64+dsw (960)
    __shared__ __align__(16) unsigned short s_wfh[P][WFS];
    __shared__ __align__(16) unsigned short s_wfl[P][WFS];
    // bufB: aw split planes (ph1->ph2, ph5->ph6) | ph3 partials
    __shared__ __align__(16) char s_bufB[16384];
    unsigned short (*s_awh)[512] = (unsigned short(*)[512])s_bufB;          // 8 KB
    unsigned short (*s_awl)[512] = (unsigned short(*)[512])(s_bufB + 8192); // 8 KB
    float (*s_part3)[16][49] = (float(*)[16][49])s_bufB;                    // 12544 B

    const int tid  = threadIdx.x;
    const int base = blockIdx.x * P;
    const int lane = tid & 63;
    const int wid  = tid >> 6;
    const int q    = lane >> 4, c = lane & 15;
    const int pg   = tid >> 5, mg = tid & 31;   // (p,m) mapping for ph1/ph5
    // NOTE: pg for wave w is {2w, 2w+1} == exactly the points ph2/ph6 wave w
    // consumes -> ph1->ph2 and ph5->ph6 need NO barrier (same-wave LDS dep).

    float nbx, nby, nbz;        // centered neighbor coords, live ph1->ph5
    bf16x8 fbh[2][4], fbl[2][4]; // cached x B-fragments (ph2 -> ph6)

    if (tid < KP * 3) ((float*)s_kp)[tid] = kpts[tid];
    if (tid < P * 3)  ((float*)s_q)[tid]  = qpts[base * 3 + tid];
    __syncthreads();

    // ---- ph1: gather, centered nb, aw1 -> split planes [p][k*32+m] ----
    {
        const int ni = nbrs[(base + pg) * M + mg];
        s_nbr[pg][mg] = ni;
        nbx = spts[ni * 3 + 0] - s_q[pg][0];
        nby = spts[ni * 3 + 1] - s_q[pg][1];
        nbz = spts[ni * 3 + 2] - s_q[pg][2];
        float av[16];
        av[15] = 0.f;                               // pad row -> exact zeros
#pragma unroll
        for (int k = 0; k < KP; k++) {
            const float dx = nbx - s_kp[k][0];
            const float dy = nby - s_kp[k][1];
            const float dz = nbz - s_kp[k][2];
            av[k] = fmaxf(1.0f - sqrtf(dx * dx + dy * dy + dz * dz), 0.f);
        }
#pragma unroll
        for (int k2 = 0; k2 < 16; k2 += 2) {
            unsigned hu, lu; split2(av[k2], av[k2 + 1], hu, lu);
            s_awh[pg][k2 * 32 + mg]       = (unsigned short)hu;
            s_awh[pg][(k2 + 1) * 32 + mg] = (unsigned short)(hu >> 16);
            s_awl[pg][k2 * 32 + mg]       = (unsigned short)lu;
            s_awl[pg][(k2 + 1) * 32 + mg] = (unsigned short)(lu >> 16);
        }
    }
    // no barrier: ph2 wave reads only its own writes (lgkmcnt ordering)

    // ---- ph2: wf1 via compensated MFMA; cache x fragments; swizzled store ----
    {
        const int hc = c >> 2;
#pragma unroll
        for (int pi = 0; pi < 2; pi++) {
            const int p = 2 * wid + pi;
            const bf16x8 ah = *(const bf16x8*)&s_awh[p][(lane & 15) * 32 + q * 8];
            const bf16x8 al = *(const bf16x8*)&s_awl[p][(lane & 15) * 32 + q * 8];
            int nbj[8];
#pragma unroll
            for (int j = 0; j < 8; j++) nbj[j] = s_nbr[p][q * 8 + j];
#pragma unroll
            for (int t = 0; t < 4; t++) {
                unsigned g[8];
#pragma unroll
                for (int j = 0; j < 8; j++)
                    g[j] = xw[nbj[j] * D + t * 16 + c];
                union { bf16x8 v; unsigned u[4]; } bh, bl;
#pragma unroll
                for (int jj = 0; jj < 4; jj++) {    // perm-unpack hi/lo planes
                    bh.u[jj] = permb(g[2 * jj + 1], g[2 * jj], 0x05040100u);
                    bl.u[jj] = permb(g[2 * jj + 1], g[2 * jj], 0x07060302u);
                }
                fbh[pi][t] = bh.v; fbl[pi][t] = bl.v;   // cache for ph6
                f32x4 dacc = {0.f, 0.f, 0.f, 0.f};
                dacc = __builtin_amdgcn_mfma_f32_16x16x32_bf16(ah, bh.v, dacc, 0, 0, 0);
                dacc = __builtin_amdgcn_mfma_f32_16x16x32_bf16(ah, bl.v, dacc, 0, 0, 0);
                dacc = __builtin_amdgcn_mfma_f32_16x16x32_bf16(al, bh.v, dacc, 0, 0, 0);
                unsigned h01, l01, h23, l23;
                split2(dacc[0], dacc[1], h01, l01);
                split2(dacc[2], dacc[3], h23, l23);
                // swizzled enum: pos = (t*16+c)*16 + 4*(q^hc) (+r)
                const int eb = (t * 16 + c) * 16 + 4 * (q ^ hc);
                *(uint2*)&s_wfh[p][eb] = make_uint2(h01, h23);
                *(uint2*)&s_wfl[p][eb] = make_uint2(l01, l23);
            }
        }
    }
    __syncthreads();

    // ---- ph3: offsets via compensated MFMA, contraction split over 4 waves ----
    {
        const int pr = lane & 7;                     // A rows 8..15 duplicate points 0..7
        f32x4 acc0 = {0,0,0,0}, acc1 = {0,0,0,0}, acc2 = {0,0,0,0};
#pragma unroll
        for (int s = 0; s < 8; s++) {
            const int ks = wid * 8 + s;
            const bf16x8 ah = *(const bf16x8*)&s_wfh[pr][ks * 32 + q * 8];
            const bf16x8 al = *(const bf16x8*)&s_wfl[pr][ks * 32 + q * 8];
#pragma unroll
            for (int nt = 0; nt < 3; nt++) {
                const int f = ((ks * 3 + nt) * 64 + lane) * 8;
                const bf16x8 bh = *(const bf16x8*)&owh[f];
                const bf16x8 bl = *(const bf16x8*)&owl[f];
                f32x4* acc = (nt == 0) ? &acc0 : (nt == 1) ? &acc1 : &acc2;
                *acc = __builtin_amdgcn_mfma_f32_16x16x32_bf16(ah, bh, *acc, 0, 0, 0);
                *acc = __builtin_amdgcn_mfma_f32_16x16x32_bf16(ah, bl, *acc, 0, 0, 0);
                *acc = __builtin_amdgcn_mfma_f32_16x16x32_bf16(al, bh, *acc, 0, 0, 0);
            }
        }
#pragma unroll
        for (int r = 0; r < 4; r++) {
            s_part3[wid][4 * q + r][0 * 16 + c] = acc0[r];
            s_part3[wid][4 * q + r][1 * 16 + c] = acc1[r];
            s_part3[wid][4 * q + r][2 * 16 + c] = acc2[r];
        }
    }
    __syncthreads();

    // ---- reduce K-partials + bias -> offsets (fp32) ----
    for (int idx = tid; idx < P * E1; idx += 256) {
        const int p = idx / E1, e = idx % E1;
        s_off[p][e] = s_part3[0][p][e] + s_part3[1][p][e] +
                      s_part3[2][p][e] + s_part3[3][p][e] + obias[e];
    }
    __syncthreads();

    // ---- ph5: aw2 (deformed kernel points) -> split planes + joint wave mask ----
    {
        unsigned pmask = 0;
        float av[16];
        av[15] = 0.f;
#pragma unroll
        for (int k = 0; k < KP; k++) {
            const float kx = s_kp[k][0] + s_off[pg][3 * k + 0];
            const float ky = s_kp[k][1] + s_off[pg][3 * k + 1];
            const float kz = s_kp[k][2] + s_off[pg][3 * k + 2];
            const float dx = nbx - kx, dy = nby - ky, dz = nbz - kz;
            av[k] = fmaxf(1.0f - sqrtf(dx * dx + dy * dy + dz * dz), 0.f);
            pmask |= (__ballot(av[k] > 0.f) ? 1u : 0u) << k;   // union of wave's 2 pts
        }
#pragma unroll
        for (int k2 = 0; k2 < 16; k2 += 2) {
            unsigned hu, lu; split2(av[k2], av[k2 + 1], hu, lu);
            s_awh[pg][k2 * 32 + mg]       = (unsigned short)hu;
            s_awh[pg][(k2 + 1) * 32 + mg] = (unsigned short)(hu >> 16);
            s_awl[pg][k2 * 32 + mg]       = (unsigned short)lu;
            s_awl[pg][(k2 + 1) * 32 + mg] = (unsigned short)(lu >> 16);
        }
        if (lane == 0) s_act[wid] = pmask;
    }
    // no barrier: ph6 wave reads only its own aw writes; s_act read after next barrier

    // ---- ph6: wf2 via compensated MFMA, operands swapped (D[d][k]) ----
    // A = cached x fragments, B = aw (identical lane mapping as A) ->
    // lane's 4 D-regs = 4 consecutive d at fixed k=c -> vector uint2 stores.
    // enum pos = k*64 + (d ^ ((k&7)<<3)); prep bakes matching d into wh/wl.
    {
#pragma unroll
        for (int pi = 0; pi < 2; pi++) {
            const int p = 2 * wid + pi;
            const bf16x8 awh_f = *(const bf16x8*)&s_awh[p][(lane & 15) * 32 + q * 8];
            const bf16x8 awl_f = *(const bf16x8*)&s_awl[p][(lane & 15) * 32 + q * 8];
#pragma unroll
            for (int t = 0; t < 4; t++) {
                const bf16x8 xh = fbh[pi][t], xl = fbl[pi][t];
                f32x4 dacc = {0.f, 0.f, 0.f, 0.f};
                dacc = __builtin_amdgcn_mfma_f32_16x16x32_bf16(xh, awh_f, dacc, 0, 0, 0);
                dacc = __builtin_amdgcn_mfma_f32_16x16x32_bf16(xh, awl_f, dacc, 0, 0, 0);
                dacc = __builtin_amdgcn_mfma_f32_16x16x32_bf16(xl, awh_f, dacc, 0, 0, 0);
                unsigned h01, l01, h23, l23;
                split2(dacc[0], dacc[1], h01, l01);
                split2(dacc[2], dacc[3], h23, l23);
                // wf2[k=c][d = t*16+4q+r]; dsw preserves 4-consecutive runs
                const int dsw = (t * 16 + 4 * q) ^ ((c & 7) << 3);
                const int eb  = c * 64 + dsw;
                *(uint2*)&s_wfh[p][eb] = make_uint2(h01, h23);
                *(uint2*)&s_wfl[p][eb] = make_uint2(l01, l23);
            }
        }
    }
    __syncthreads();

    const unsigned u2 = s_act[0] | s_act[1] | s_act[2] | s_act[3];

    // ---- ph7: output via compensated MFMA over active k; wave = e-tile ----
    {
        const int pr = lane & 7;                    // A rows 8..15 duplicate points 0..7
        f32x4 acc = {0.f, 0.f, 0.f, 0.f};
#pragma unroll
        for (int k = 0; k < KP; k++) {
            if (!((u2 >> k) & 1)) continue;
#pragma unroll
            for (int kk = 0; kk < 2; kk++) {
                const int ks = k * 2 + kk;          // pos chunk: k = ks>>1
                const bf16x8 ah = *(const bf16x8*)&s_wfh[pr][ks * 32 + q * 8];
                const bf16x8 al = *(const bf16x8*)&s_wfl[pr][ks * 32 + q * 8];
                const int f = ((ks * 4 + wid) * 64 + lane) * 8;
                const bf16x8 bh = *(const bf16x8*)&wh[f];
                const bf16x8 bl = *(const bf16x8*)&wl[f];
                acc = __builtin_amdgcn_mfma_f32_16x16x32_bf16(ah, bh, acc, 0, 0, 0);
                acc = __builtin_amdgcn_mfma_f32_16x16x32_bf16(ah, bl, acc, 0, 0, 0);
                acc = __builtin_amdgcn_mfma_f32_16x16x32_bf16(al, bh, acc, 0, 0, 0);
            }
        }
        // D rows 0..7 = points (rows 8..15 duplicates); direct coalesced store
        if (q < 2) {
#pragma unroll
            for (int r = 0; r < 4; r++)
                out[(base + 4 * q + r) * D + wid * 16 + c] = acc[r];
        }
    }
}

extern "C" void kernel_launch(void* const* d_in, const int* in_sizes, int n_in,
                              void* d_out, int out_size, void* d_ws, size_t ws_size,
                              hipStream_t stream) {
    const float* q   = (const float*)d_in[0];
    const float* s   = (const float*)d_in[1];
    const int*   nb  = (const int*)  d_in[2];
    const float* x   = (const float*)d_in[3];
    const float* kp  = (const float*)d_in[4];
    const float* ow  = (const float*)d_in[5];
    const float* ob  = (const float*)d_in[6];
    const float* w   = (const float*)d_in[7];
    float* out = (float*)d_out;

    unsigned*       xw  = (unsigned*)d_ws;                            // 12,800,000 B
    unsigned short* owh = (unsigned short*)((char*)d_ws + 12800000);  //     98,304 B
    unsigned short* owl = (unsigned short*)((char*)d_ws + 12898304);  //     98,304 B
    unsigned short* wh  = (unsigned short*)((char*)d_ws + 12996608);  //    122,880 B
    unsigned short* wl  = (unsigned short*)((char*)d_ws + 13119488);  //    122,880 B

    prep_all<<<12932, 256, 0, stream>>>(x, ow, w, xw, owh, owl, wh, wl);
    kpconv_deform<<<N_PTS / P, 256, 0, stream>>>(q, s, nb, kp, ob,
                                                 xw, owh, owl, wh, wl, out);
}

// Round 15
// 207.390 us; speedup vs baseline: 3.9417x; 1.0598x over previous
//
#include <hip/hip_runtime.h>

#define N_PTS 50000
#define M 32
#define KP 15
#define D 64
#define E1 45
#define P 8
#define WFS 1048   // wf plane row stride (ushorts): >=1024 enum slots

typedef __attribute__((ext_vector_type(8))) _Float16 f16x8;
typedef __attribute__((ext_vector_type(4))) float    f32x4;
typedef __attribute__((ext_vector_type(2))) _Float16 f16x2;
typedef __attribute__((ext_vector_type(2))) __fp16   fp16v2;   // builtin return type

__device__ __forceinline__ unsigned pkrtz(float a, float b) {   // packed fp16 RTZ
    union { fp16v2 v; unsigned u; } x;
    x.v = __builtin_amdgcn_cvt_pkrtz(a, b);
    return x.u;
}
__device__ __forceinline__ unsigned pkrne(float a, float b) {   // packed fp16 RNE
    union { f16x2 v; unsigned u; } x;
    x.v[0] = (_Float16)a; x.v[1] = (_Float16)b; return x.u;
}
__device__ __forceinline__ float h2f(unsigned bits16) {
    union { unsigned short s; _Float16 h; } x; x.s = (unsigned short)bits16;
    return (float)x.h;
}
// compensated fp16 split of a pair: hu = packed hi (RTZ), lu = packed residual
__device__ __forceinline__ void split2h(float a, float b, unsigned& hu, unsigned& lu) {
    hu = pkrtz(a, b);
    const float ra = a - h2f(hu & 0xffffu);
    const float rb = b - h2f(hu >> 16);
    lu = pkrtz(ra, rb);
}
// packed single value split: lo16 = fp16 hi (RNE), hi16 = fp16 residual
__device__ __forceinline__ unsigned splitpk1(float v) {
    const _Float16 h = (_Float16)v;
    const _Float16 l = (_Float16)(v - (float)h);
    union { f16x2 v2; unsigned u; } x; x.v2[0] = h; x.v2[1] = l; return x.u;
}

#if defined(__HIP_DEVICE_COMPILE__) && __has_builtin(__builtin_amdgcn_perm)
__device__ __forceinline__ unsigned permb(unsigned a, unsigned b, unsigned sel) {
    return __builtin_amdgcn_perm(a, b, sel);
}
#else
__device__ __forceinline__ unsigned permb(unsigned a, unsigned b, unsigned sel) {
    if (sel == 0x05040100u) return (b & 0xffffu) | (a << 16);
    return (b >> 16) | (a & 0xffff0000u);
}
#endif

// ---------------- fused prep (one launch; writes d_ws) -----------------------
// blocks [0,12500): x -> packed {f16 hi, f16 residual} dwords
// blocks [12500,12692): ow -> owh/owl fp16 planes; pos swizzle:
//     orig = pos ^ (((pos>>6)&3)<<2); d = orig>>4, k = orig&15 (zero pad k==15/e>=45)
// blocks [12692,12932): w -> wh single fp16 plane; pos = k*64+dsw, d = dsw ^ ((k&7)<<3)
__global__ void prep_all(const float* __restrict__ x, const float* __restrict__ ow,
                         const float* __restrict__ w, unsigned* __restrict__ xw,
                         unsigned short* __restrict__ owh, unsigned short* __restrict__ owl,
                         unsigned short* __restrict__ wh)
{
    const int b = blockIdx.x, tid = threadIdx.x;
    if (b < 12500) {
        const int i = b * 256 + tid;
        xw[i] = splitpk1(x[i]);
    } else if (b < 12692) {
        const int t = (b - 12500) * 256 + tid;              // [0, 49152)
        const int j = t & 7, lane = (t >> 3) & 63, rest = t >> 9;
        const int nt = rest % 3, ks = rest / 3;
        const int q = lane >> 4, c = lane & 15;
        const int pos  = ks * 32 + q * 8 + j;
        const int orig = pos ^ (((pos >> 6) & 3) << 2);
        const int d = orig >> 4, k = orig & 15, e = nt * 16 + c;
        const float v = (k < KP && e < E1) ? ow[k * (D * E1) + d * E1 + e] : 0.f;
        const unsigned u = splitpk1(v);
        owh[t] = (unsigned short)u;
        owl[t] = (unsigned short)(u >> 16);
    } else {
        const int t = (b - 12692) * 256 + tid;              // [0, 61440)
        const int j = t & 7, lane = (t >> 3) & 63, rest = t >> 9;
        const int nt = rest & 3, ks = rest >> 2;            // ks in [0,30)
        const int q = lane >> 4, c = lane & 15;
        const int pos = ks * 32 + q * 8 + j;                // [0,960)
        const int k = pos >> 6, dsw = pos & 63;
        const int d = dsw ^ ((k & 7) << 3);
        const int e = nt * 16 + c;
        union { _Float16 h; unsigned short s; } cv;
        cv.h = (_Float16)w[k * (D * D) + d * D + e];        // RNE single fp16
        wh[t] = cv.s;
    }
}

__global__ __launch_bounds__(256, 3) void kpconv_deform(
    const float* __restrict__ qpts, const float* __restrict__ spts,
    const int*   __restrict__ nbrs, const float* __restrict__ kpts,
    const float* __restrict__ obias,
    const unsigned* __restrict__ xw,
    const unsigned short* __restrict__ owh, const unsigned short* __restrict__ owl,
    const unsigned short* __restrict__ wh,
    float* __restrict__ out)
{
    __shared__ int   s_nbr[P][M];
    __shared__ float s_kp[KP][3];
    __shared__ float s_q[P][3];
    __shared__ float s_off[P][E1];
    __shared__ unsigned s_act[4];
    // wf planes: ph2->ph3 compensated pair enum (1024); ph6->ph7 single, k*64+dsw
    __shared__ __align__(16) unsigned short s_wfh[P][WFS];
    __shared__ __align__(16) unsigned short s_wfl[P][WFS];   // first half only
    // bufB: aw planes (pairs first half; hi-only second half) | ph3 partials
    __shared__ __align__(16) char s_bufB[16384];
    unsigned short (*s_awh)[512] = (unsigned short(*)[512])s_bufB;          // 8 KB
    unsigned short (*s_awl)[512] = (unsigned short(*)[512])(s_bufB + 8192); // 8 KB
    float (*s_part3)[16][49] = (float(*)[16][49])s_bufB;                    // 12544 B

    const int tid  = threadIdx.x;
    const int base = blockIdx.x * P;
    const int lane = tid & 63;
    const int wid  = tid >> 6;
    const int q    = lane >> 4, c = lane & 15;
    const int pg   = tid >> 5, mg = tid & 31;   // (p,m) mapping for ph1/ph5
    // wave w's ph1/ph5 points {2w,2w+1} == its ph2/ph6 consumers -> no barrier needed

    float nbx, nby, nbz;   // centered neighbor coords, live ph1->ph5
    f16x8 fbh[2][4];       // cached x hi fragments (ph2 -> ph6)

    if (tid < KP * 3) ((float*)s_kp)[tid] = kpts[tid];
    if (tid < P * 3)  ((float*)s_q)[tid]  = qpts[base * 3 + tid];
    __syncthreads();

    // ---- ph1: gather, centered nb, aw1 -> compensated fp16 planes [p][k*32+m] ----
    {
        const int ni = nbrs[(base + pg) * M + mg];
        s_nbr[pg][mg] = ni;
        nbx = spts[ni * 3 + 0] - s_q[pg][0];
        nby = spts[ni * 3 + 1] - s_q[pg][1];
        nbz = spts[ni * 3 + 2] - s_q[pg][2];
        float av[16];
        av[15] = 0.f;                               // pad row -> exact zeros
#pragma unroll
        for (int k = 0; k < KP; k++) {
            const float dx = nbx - s_kp[k][0];
            const float dy = nby - s_kp[k][1];
            const float dz = nbz - s_kp[k][2];
            av[k] = fmaxf(1.0f - sqrtf(dx * dx + dy * dy + dz * dz), 0.f);
        }
#pragma unroll
        for (int k2 = 0; k2 < 16; k2 += 2) {
            unsigned hu, lu; split2h(av[k2], av[k2 + 1], hu, lu);
            s_awh[pg][k2 * 32 + mg]       = (unsigned short)hu;
            s_awh[pg][(k2 + 1) * 32 + mg] = (unsigned short)(hu >> 16);
            s_awl[pg][k2 * 32 + mg]       = (unsigned short)lu;
            s_awl[pg][(k2 + 1) * 32 + mg] = (unsigned short)(lu >> 16);
        }
    }
    // no barrier: ph2 wave reads only its own writes (lgkmcnt ordering)

    // ---- ph2: wf1 via compensated f16 MFMA; cache x hi fragments ----
    {
        const int hc = c >> 2;
#pragma unroll
        for (int pi = 0; pi < 2; pi++) {
            const int p = 2 * wid + pi;
            const f16x8 ah = *(const f16x8*)&s_awh[p][(lane & 15) * 32 + q * 8];
            const f16x8 al = *(const f16x8*)&s_awl[p][(lane & 15) * 32 + q * 8];
            int nbj[8];
#pragma unroll
            for (int j = 0; j < 8; j++) nbj[j] = s_nbr[p][q * 8 + j];
#pragma unroll
            for (int t = 0; t < 4; t++) {
                unsigned g[8];
#pragma unroll
                for (int j = 0; j < 8; j++)
                    g[j] = xw[nbj[j] * D + t * 16 + c];
                union { f16x8 v; unsigned u[4]; } bh, bl;
#pragma unroll
                for (int jj = 0; jj < 4; jj++) {    // perm-unpack hi/lo planes
                    bh.u[jj] = permb(g[2 * jj + 1], g[2 * jj], 0x05040100u);
                    bl.u[jj] = permb(g[2 * jj + 1], g[2 * jj], 0x07060302u);
                }
                fbh[pi][t] = bh.v;                   // cache hi for ph6
                f32x4 dacc = {0.f, 0.f, 0.f, 0.f};
                dacc = __builtin_amdgcn_mfma_f32_16x16x32_f16(ah, bh.v, dacc, 0, 0, 0);
                dacc = __builtin_amdgcn_mfma_f32_16x16x32_f16(ah, bl.v, dacc, 0, 0, 0);
                dacc = __builtin_amdgcn_mfma_f32_16x16x32_f16(al, bh.v, dacc, 0, 0, 0);
                unsigned h01, l01, h23, l23;
                split2h(dacc[0], dacc[1], h01, l01);
                split2h(dacc[2], dacc[3], h23, l23);
                // swizzled enum: pos = (t*16+c)*16 + 4*(q^hc) (+r)
                const int eb = (t * 16 + c) * 16 + 4 * (q ^ hc);
                *(uint2*)&s_wfh[p][eb] = make_uint2(h01, h23);
                *(uint2*)&s_wfl[p][eb] = make_uint2(l01, l23);
            }
        }
    }
    __syncthreads();

    // ---- ph3: offsets via compensated f16 MFMA, contraction split over 4 waves ----
    {
        const int pr = lane & 7;                     // A rows 8..15 duplicate points 0..7
        f32x4 acc0 = {0,0,0,0}, acc1 = {0,0,0,0}, acc2 = {0,0,0,0};
#pragma unroll
        for (int s = 0; s < 8; s++) {
            const int ks = wid * 8 + s;
            const f16x8 ah = *(const f16x8*)&s_wfh[pr][ks * 32 + q * 8];
            const f16x8 al = *(const f16x8*)&s_wfl[pr][ks * 32 + q * 8];
#pragma unroll
            for (int nt = 0; nt < 3; nt++) {
                const int f = ((ks * 3 + nt) * 64 + lane) * 8;
                const f16x8 bh = *(const f16x8*)&owh[f];
                const f16x8 bl = *(const f16x8*)&owl[f];
                f32x4* acc = (nt == 0) ? &acc0 : (nt == 1) ? &acc1 : &acc2;
                *acc = __builtin_amdgcn_mfma_f32_16x16x32_f16(ah, bh, *acc, 0, 0, 0);
                *acc = __builtin_amdgcn_mfma_f32_16x16x32_f16(ah, bl, *acc, 0, 0, 0);
                *acc = __builtin_amdgcn_mfma_f32_16x16x32_f16(al, bh, *acc, 0, 0, 0);
            }
        }
#pragma unroll
        for (int r = 0; r < 4; r++) {
            s_part3[wid][4 * q + r][0 * 16 + c] = acc0[r];
            s_part3[wid][4 * q + r][1 * 16 + c] = acc1[r];
            s_part3[wid][4 * q + r][2 * 16 + c] = acc2[r];
        }
    }
    __syncthreads();

    // ---- reduce K-partials + bias -> offsets (fp32) ----
    for (int idx = tid; idx < P * E1; idx += 256) {
        const int p = idx / E1, e = idx % E1;
        s_off[p][e] = s_part3[0][p][e] + s_part3[1][p][e] +
                      s_part3[2][p][e] + s_part3[3][p][e] + obias[e];
    }
    __syncthreads();

    // ---- ph5: aw2 (deformed) -> single fp16 plane (RNE) + joint wave mask ----
    {
        unsigned pmask = 0;
        float av[16];
        av[15] = 0.f;
#pragma unroll
        for (int k = 0; k < KP; k++) {
            const float kx = s_kp[k][0] + s_off[pg][3 * k + 0];
            const float ky = s_kp[k][1] + s_off[pg][3 * k + 1];
            const float kz = s_kp[k][2] + s_off[pg][3 * k + 2];
            const float dx = nbx - kx, dy = nby - ky, dz = nbz - kz;
            av[k] = fmaxf(1.0f - sqrtf(dx * dx + dy * dy + dz * dz), 0.f);
            pmask |= (__ballot(av[k] > 0.f) ? 1u : 0u) << k;   // union of wave's 2 pts
        }
#pragma unroll
        for (int k2 = 0; k2 < 16; k2 += 2) {
            const unsigned hu = pkrne(av[k2], av[k2 + 1]);
            s_awh[pg][k2 * 32 + mg]       = (unsigned short)hu;
            s_awh[pg][(k2 + 1) * 32 + mg] = (unsigned short)(hu >> 16);
        }
        if (lane == 0) s_act[wid] = pmask;
    }
    // no barrier: ph6 wave reads only its own aw writes; s_act read after next barrier

    // ---- ph6: wf2 via single f16 MFMA, operands swapped (D[d][k]) ----
    {
#pragma unroll
        for (int pi = 0; pi < 2; pi++) {
            const int p = 2 * wid + pi;
            const f16x8 awh_f = *(const f16x8*)&s_awh[p][(lane & 15) * 32 + q * 8];
#pragma unroll
            for (int t = 0; t < 4; t++) {
                f32x4 dacc = {0.f, 0.f, 0.f, 0.f};
                dacc = __builtin_amdgcn_mfma_f32_16x16x32_f16(fbh[pi][t], awh_f, dacc, 0, 0, 0);
                // wf2[k=c][d = t*16+4q+r] single fp16 (RNE); dsw keeps 4-runs
                const unsigned u01 = pkrne(dacc[0], dacc[1]);
                const unsigned u23 = pkrne(dacc[2], dacc[3]);
                const int dsw = (t * 16 + 4 * q) ^ ((c & 7) << 3);
                *(uint2*)&s_wfh[p][c * 64 + dsw] = make_uint2(u01, u23);
            }
        }
    }
    __syncthreads();

    const unsigned u2 = s_act[0] | s_act[1] | s_act[2] | s_act[3];

    // ---- ph7: output via single f16 MFMA over active k; wave = e-tile ----
    {
        const int pr = lane & 7;                    // A rows 8..15 duplicate points 0..7
        f32x4 acc = {0.f, 0.f, 0.f, 0.f};
#pragma unroll
        for (int k = 0; k < KP; k++) {
            if (!((u2 >> k) & 1)) continue;
#pragma unroll
            for (int kk = 0; kk < 2; kk++) {
                const int ks = k * 2 + kk;          // pos chunk: k = ks>>1
                const f16x8 ah = *(const f16x8*)&s_wfh[pr][ks * 32 + q * 8];
                const f16x8 bh = *(const f16x8*)&wh[((ks * 4 + wid) * 64 + lane) * 8];
                acc = __builtin_amdgcn_mfma_f32_16x16x32_f16(ah, bh, acc, 0, 0, 0);
            }
        }
        // D rows 0..7 = points (rows 8..15 duplicates); direct coalesced store
        if (q < 2) {
#pragma unroll
            for (int r = 0; r < 4; r++)
                out[(base + 4 * q + r) * D + wid * 16 + c] = acc[r];
        }
    }
}

extern "C" void kernel_launch(void* const* d_in, const int* in_sizes, int n_in,
                              void* d_out, int out_size, void* d_ws, size_t ws_size,
                              hipStream_t stream) {
    const float* q   = (const float*)d_in[0];
    const float* s   = (const float*)d_in[1];
    const int*   nb  = (const int*)  d_in[2];
    const float* x   = (const float*)d_in[3];
    const float* kp  = (const float*)d_in[4];
    const float* ow  = (const float*)d_in[5];
    const float* ob  = (const float*)d_in[6];
    const float* w   = (const float*)d_in[7];
    float* out = (float*)d_out;

    unsigned*       xw  = (unsigned*)d_ws;                            // 12,800,000 B
    unsigned short* owh = (unsigned short*)((char*)d_ws + 12800000);  //     98,304 B
    unsigned short* owl = (unsigned short*)((char*)d_ws + 12898304);  //     98,304 B
    unsigned short* wh  = (unsigned short*)((char*)d_ws + 12996608);  //    122,880 B

    prep_all<<<12932, 256, 0, stream>>>(x, ow, w, xw, owh, owl, wh);
    kpconv_deform<<<N_PTS / P, 256, 0, stream>>>(q, s, nb, kp, ob,
                                                 xw, owh, owl, wh, out);
}